// Round 4
// baseline (714.401 us; speedup 1.0000x reference)
//
#include <hip/hip_runtime.h>

typedef unsigned short u16;
typedef __attribute__((ext_vector_type(8))) short short8;
typedef __attribute__((ext_vector_type(4))) float f32x4;
typedef __attribute__((ext_vector_type(4))) int i32x4;

// ---------- bf16 helpers (RNE) ----------
__device__ __forceinline__ float bf2f(u16 u) {
  union { unsigned u; float f; } v; v.u = ((unsigned)u) << 16; return v.f;
}
__device__ __forceinline__ u16 f2bf(float f) {
  union { float f; unsigned u; } v; v.f = f;
  unsigned r = (v.u + 0x7FFFu + ((v.u >> 16) & 1u)) >> 16;
  return (u16)r;
}
__device__ __forceinline__ float flushv(float t, float sentinel) {
  if (t != t || fabsf(t) > 3.0e38f) return sentinel;
  return t;
}
// load 8 fp32 and convert to bf16x8
__device__ __forceinline__ short8 ld8f(const float* p) {
  const float4 f0 = *(const float4*)p;
  const float4 f1 = *(const float4*)(p + 4);
  short8 r;
  r[0] = (short)f2bf(f0.x); r[1] = (short)f2bf(f0.y);
  r[2] = (short)f2bf(f0.z); r[3] = (short)f2bf(f0.w);
  r[4] = (short)f2bf(f1.x); r[5] = (short)f2bf(f1.y);
  r[6] = (short)f2bf(f1.z); r[7] = (short)f2bf(f1.w);
  return r;
}

// un-sinkable 16B global load (compiler cannot track or move it)
#define GLD(dst, ptr, OFF) \
  asm volatile("global_load_dwordx4 %0, %1, off offset:" OFF \
               : "=v"(dst) : "v"(ptr))
// manually counted wait + full scheduling fence (rule #18)
#define WAITV(N) do { \
  asm volatile("s_waitcnt vmcnt(" #N ")" ::: "memory"); \
  __builtin_amdgcn_sched_barrier(0); } while (0)

// ================= GEMM: C[M,N] = A[M,K] @ W[N,K]^T =================
// AF/WF: operand is fp32 in global (convert to bf16 at staging). OF: output fp32.
// m93 structure: 128x128 tile, BK=32, VGPR staging, 2 barriers, 16x16x32 MFMA.
template <bool AF, bool WF, bool OF>
__global__ __launch_bounds__(256) void gemm_bt(
    const void* __restrict__ Ap,
    const void* __restrict__ Wp0, const void* __restrict__ Wp1, const void* __restrict__ Wp2,
    void* __restrict__ O0, void* __restrict__ O1, void* __restrict__ O2,
    int M, int N, int K, float sentinel)
{
  __shared__ __align__(16) u16 As[128 * 32];
  __shared__ __align__(16) u16 Bs[128 * 32];

  const void* Wp; void* O;
  if (blockIdx.z == 0)      { Wp = Wp0; O = O0; }
  else if (blockIdx.z == 1) { Wp = Wp1; O = O1; }
  else                      { Wp = Wp2; O = O2; }

  const float* Af = (const float*)Ap;  const u16* Ab = (const u16*)Ap;
  const float* Wf = (const float*)Wp;  const u16* Wb = (const u16*)Wp;

  const int tid  = threadIdx.x;
  const int wave = tid >> 6;
  const int lane = tid & 63;
  const int quad = lane >> 4;
  const int l15  = lane & 15;

  const int m0 = blockIdx.y * 128;
  const int n0 = blockIdx.x * 128;
  const int wm = (wave >> 1) * 64;
  const int wn = (wave & 1) * 64;

  const int e0 = wave * 1024 + lane * 8;
  const int e1 = e0 + 512;
  const int r0 = e0 >> 5, c0 = e0 & 31;
  const int r1 = e1 >> 5, c1 = e1 & 31;

  const long aoff0 = (long)(m0 + r0) * K + c0;
  const long aoff1 = (long)(m0 + r1) * K + c1;
  const long boff0 = (long)(n0 + r0) * K + c0;
  const long boff1 = (long)(n0 + r1) * K + c1;

  const f32x4 zero = {0.f, 0.f, 0.f, 0.f};
  f32x4 acc[4][4];
#pragma unroll
  for (int i = 0; i < 4; ++i)
#pragma unroll
    for (int j = 0; j < 4; ++j) acc[i][j] = zero;

  for (int k0 = 0; k0 < K; k0 += 32) {
    short8 a0, a1, b0, b1;
    if constexpr (AF) {
      a0 = ld8f(Af + aoff0 + k0);
      a1 = ld8f(Af + aoff1 + k0);
    } else {
      a0 = *(const short8*)(Ab + aoff0 + k0);
      a1 = *(const short8*)(Ab + aoff1 + k0);
    }
    if constexpr (WF) {
      b0 = ld8f(Wf + boff0 + k0);
      b1 = ld8f(Wf + boff1 + k0);
    } else {
      b0 = *(const short8*)(Wb + boff0 + k0);
      b1 = *(const short8*)(Wb + boff1 + k0);
    }

    __syncthreads();
    *(short8*)&As[e0] = a0;
    *(short8*)&As[e1] = a1;
    *(short8*)&Bs[e0] = b0;
    *(short8*)&Bs[e1] = b1;
    __syncthreads();

    short8 af[4], bf[4];
#pragma unroll
    for (int i = 0; i < 4; ++i)
      af[i] = *(const short8*)&As[(wm + i * 16 + l15) * 32 + quad * 8];
#pragma unroll
    for (int j = 0; j < 4; ++j)
      bf[j] = *(const short8*)&Bs[(wn + j * 16 + l15) * 32 + quad * 8];
#pragma unroll
    for (int i = 0; i < 4; ++i)
#pragma unroll
      for (int j = 0; j < 4; ++j)
        acc[i][j] = __builtin_amdgcn_mfma_f32_16x16x32_bf16(af[i], bf[j], acc[i][j], 0, 0, 0);
  }

  // C/D layout: col = lane&15, row = quad*4 + reg (verified m89/m91)
#pragma unroll
  for (int i = 0; i < 4; ++i) {
    const int row0 = m0 + wm + i * 16 + quad * 4;
#pragma unroll
    for (int j = 0; j < 4; ++j) {
      const int col = n0 + wn + j * 16 + l15;
#pragma unroll
      for (int r = 0; r < 4; ++r) {
        const float val = flushv(acc[i][j][r], sentinel);
        if constexpr (OF)
          ((float*)O)[(long)(row0 + r) * N + col] = val;
        else
          ((u16*)O)[(long)(row0 + r) * N + col] = f2bf(val);
      }
    }
  }
}

// ================= RoPE (chunk-half), in-place on bf16 Q and K =================
__global__ __launch_bounds__(256) void rope_kernel(u16* __restrict__ Q, u16* __restrict__ K)
{
  int t = blockIdx.x * 256 + threadIdx.x;
  const int half = 2 * 2048 * 16 * 64;
  u16* P = Q;
  if (t >= half) { P = K; t -= half; }
  const int i = t & 63;
  const int s = (t >> 10) & 2047;
  const long off = ((long)(t >> 6) << 7) + i;

  const float inv_freq = __expf((float)i * -0.14391156831212787f);  // 10000^(-i/64)
  const float fr = (float)s * inv_freq;
  float sn, cs;
  __sincosf(fr, &sn, &cs);

  const float q1 = bf2f(P[off]);
  const float q2 = bf2f(P[off + 64]);
  P[off]      = f2bf(q1 * cs - q2 * sn);
  P[off + 64] = f2bf(q1 * sn + q2 * cs);
}

// ================= causal flash attention (hand-scheduled asm pipeline) =================
// Q,K: [b,s,h*128+d] bf16.  VT: [h*128+d][b*2048+s] bf16 (pre-transposed by gemm).
// ALL loads are asm volatile global_load_dwordx4 (compiler cannot sink them — R3's
// VGPR=84 proved intrinsic loads get sunk at IR level). Manually counted vmcnt:
//   steady state 16 loads in flight (K[jb+1] 8 + V[jb] or V[jb+1] 8).
//   loop top:  vmcnt(8) -> K[jb] ready (V still flying)  -> QK
//   pre-PV:    vmcnt(8) -> V[jb] ready (K[jb+1] flying)  -> PV
// Each wait is followed by sched_barrier(0) so MFMAs can't hoist above it (rule #18).
// Last iteration: K-issue runs unguarded (overruns into adjacent ws region, safe);
// V-issue is guarded (would run past workspace end). vmcnt(0) before epilogue.
__global__ __launch_bounds__(256, 3) void attn_kernel(
    const u16* __restrict__ Q, const u16* __restrict__ K,
    const u16* __restrict__ VT, u16* __restrict__ AO)
{
  __shared__ float St[4][32 * 17];   // per-wave S^T[key][q], stride 17 (2-way banks)

  const int tid  = threadIdx.x;
  const int wave = tid >> 6;
  const int lane = tid & 63;
  const int quad = lane >> 4;
  const int l15  = lane & 15;
  const int row4 = lane >> 2;   // softmax: q-row owned by this lane group
  const int sub  = lane & 3;    // 4 lanes per row, 8 cols each

  // XCD-aware remap + LPT (see R1/R2 notes)
  const int lin = blockIdx.x;                        // grid 1024, 1-D
  const int xcd = lin & 7;
  const int idx = lin >> 3;                          // 0..127
  const int qb  = 31 - (idx >> 2);                   // 31..0 descending globally
  const int bh  = (xcd << 2) | (idx & 3);            // bijective: 8*4 = 32 bh values
  const int b   = bh >> 4;
  const int h   = bh & 15;

  const long base = (long)b * 2048 * 2048 + (long)h * 128;
  const long vtb  = (long)h * 128 * 4096 + (long)b * 2048;
  const int q0w = qb * 64 + wave * 16;

  // ---- Q fragments via asm loads, drained before the pipeline starts ----
  short8 qa[4];
  {
    const u16* qp = Q + base + (long)(q0w + l15) * 2048 + quad * 8;
    GLD(qa[0], qp, "0"); GLD(qa[1], qp, "64");
    GLD(qa[2], qp, "128"); GLD(qa[3], qp, "192");
  }
  WAITV(0);

  // ---- K/V pointers ----
  const u16* kA = K + base + (long)l15 * 2048 + quad * 8;        // rows l15 + j0
  const u16* kB = kA + 16 * 2048;                                // rows l15+16 + j0
  const u16* vP0 = VT + vtb + (long)(0 * 16 + l15) * 4096 + quad * 8;
  const u16* vP1 = vP0 + 1 * 16 * 4096;
  const u16* vP2 = vP0 + 2 * 16 * 4096;
  const u16* vP3 = vP0 + 3 * 16 * 4096;
  const u16* vP4 = vP0 + 4 * 16 * 4096;
  const u16* vP5 = vP0 + 5 * 16 * 4096;
  const u16* vP6 = vP0 + 6 * 16 * 4096;
  const u16* vP7 = vP0 + 7 * 16 * 4096;

  short8 kb[8], vb[8];
  // prologue: issue K[0] (8 loads) then V[0] (8 loads) -> 16 in flight
  GLD(kb[0], kA, "0"); GLD(kb[1], kA, "64"); GLD(kb[2], kA, "128"); GLD(kb[3], kA, "192");
  GLD(kb[4], kB, "0"); GLD(kb[5], kB, "64"); GLD(kb[6], kB, "128"); GLD(kb[7], kB, "192");
  GLD(vb[0], vP0, "0"); GLD(vb[1], vP1, "0"); GLD(vb[2], vP2, "0"); GLD(vb[3], vP3, "0");
  GLD(vb[4], vP4, "0"); GLD(vb[5], vP5, "0"); GLD(vb[6], vP6, "0"); GLD(vb[7], vP7, "0");

  const f32x4 zero = {0.f, 0.f, 0.f, 0.f};
  f32x4 o[8];
#pragma unroll
  for (int c = 0; c < 8; ++c) o[c] = zero;

  float mreg = -1e30f, lreg = 0.f;   // running max / denom for row row4
  float* S = St[wave];
  const float scale = 0.08838834764831845f;  // 1/sqrt(128)
  const int qi = q0w + row4;
  const int psrc = (l15 << 2) | quad;        // src lane for P fragment shuffle

  // waves 0-1 skip the fully-masked last tile; exactly ONE tile per wave straddles
  // the diagonal (jb == njb-1); masking is branch-skipped elsewhere.
  const int njb = qb * 2 + 1 + (wave >> 1);

  for (int jb = 0; jb < njb; ++jb) {
    const int j0 = jb * 32;

    // ---- K[jb] ready (V[jb] still in flight: 8 outstanding) ----
    WAITV(8);
    __builtin_amdgcn_s_setprio(1);
    f32x4 s0 = zero, s1 = zero;
#pragma unroll
    for (int c = 0; c < 4; ++c) {
      s0 = __builtin_amdgcn_mfma_f32_16x16x32_bf16(qa[c], kb[c],     s0, 0, 0, 0);
      s1 = __builtin_amdgcn_mfma_f32_16x16x32_bf16(qa[c], kb[c + 4], s1, 0, 0, 0);
    }
    __builtin_amdgcn_s_setprio(0);

    // ---- issue K[jb+1] in place (last iter overruns into v-region: safe, unused) ----
    kA += 32 * 2048; kB += 32 * 2048;
    GLD(kb[0], kA, "0"); GLD(kb[1], kA, "64"); GLD(kb[2], kA, "128"); GLD(kb[3], kA, "192");
    GLD(kb[4], kB, "0"); GLD(kb[5], kB, "64"); GLD(kb[6], kB, "128"); GLD(kb[7], kB, "192");

    // ---- layout swap via per-wave S^T LDS (2-way banks: free) ----
#pragma unroll
    for (int r = 0; r < 4; ++r) {
      S[l15 * 17 + quad * 4 + r]        = s0[r];
      S[(l15 + 16) * 17 + quad * 4 + r] = s1[r];
    }
    __builtin_amdgcn_wave_barrier();

    // ---- online softmax: row row4, 4 lanes x 8 cols ----
    float sv[8];
    float pmax = -1e30f;
    if (j0 + 31 > q0w) {               // wave-uniform: only the diagonal tile
#pragma unroll
      for (int j = 0; j < 8; ++j) {
        const int col = sub * 8 + j;
        float s = S[col * 17 + row4] * scale;
        if (j0 + col > qi) s = -1e30f;
        sv[j] = s;
        pmax = fmaxf(pmax, s);
      }
    } else {
#pragma unroll
      for (int j = 0; j < 8; ++j) {
        float s = S[(sub * 8 + j) * 17 + row4] * scale;
        sv[j] = s;
        pmax = fmaxf(pmax, s);
      }
    }
    __builtin_amdgcn_wave_barrier();
    pmax = fmaxf(pmax, __shfl_xor(pmax, 1, 64));
    pmax = fmaxf(pmax, __shfl_xor(pmax, 2, 64));
    const float mprev = mreg;
    const float mnew  = fmaxf(mprev, pmax);
    const float alpha = __expf(mprev - mnew);   // first tile: exp(-1e30) = 0, o==0 anyway
    float psum = 0.f;
#pragma unroll
    for (int j = 0; j < 8; ++j) {
      sv[j] = __expf(sv[j] - mnew);             // masked cols underflow to 0
      psum += sv[j];
    }
    psum += __shfl_xor(psum, 1, 64);
    psum += __shfl_xor(psum, 2, 64);
    lreg = lreg * alpha + psum;
    mreg = mnew;

    // ---- P pack (v_cvt_pk_bf16_f32, RNE) + A-fragment shuffle ----
    i32x4 pi;
    asm("v_cvt_pk_bf16_f32 %0, %1, %2" : "=v"(pi[0]) : "v"(sv[0]), "v"(sv[1]));
    asm("v_cvt_pk_bf16_f32 %0, %1, %2" : "=v"(pi[1]) : "v"(sv[2]), "v"(sv[3]));
    asm("v_cvt_pk_bf16_f32 %0, %1, %2" : "=v"(pi[2]) : "v"(sv[4]), "v"(sv[5]));
    asm("v_cvt_pk_bf16_f32 %0, %1, %2" : "=v"(pi[3]) : "v"(sv[6]), "v"(sv[7]));
    i32x4 pt;
    pt[0] = __shfl(pi[0], psrc, 64);
    pt[1] = __shfl(pi[1], psrc, 64);
    pt[2] = __shfl(pi[2], psrc, 64);
    pt[3] = __shfl(pi[3], psrc, 64);
    const short8 pa = *(const short8*)&pt;

    // ---- rescale O by alpha of rows quad*4+r (broadcast via shuffle) ----
    float av[4];
#pragma unroll
    for (int r = 0; r < 4; ++r) av[r] = __shfl(alpha, (quad * 4 + r) << 2, 64);
#pragma unroll
    for (int c = 0; c < 8; ++c) {
      o[c][0] *= av[0]; o[c][1] *= av[1]; o[c][2] *= av[2]; o[c][3] *= av[3];
    }

    // ---- V[jb] ready (K[jb+1] in flight: 8 outstanding) ----
    WAITV(8);
    __builtin_amdgcn_s_setprio(1);
#pragma unroll
    for (int c = 0; c < 8; ++c)
      o[c] = __builtin_amdgcn_mfma_f32_16x16x32_bf16(pa, vb[c], o[c], 0, 0, 0);
    __builtin_amdgcn_s_setprio(0);

    // ---- issue V[jb+1] (guarded: last-iter address would leave the workspace) ----
    if (jb + 1 < njb) {
      vP0 += 32; vP1 += 32; vP2 += 32; vP3 += 32;
      vP4 += 32; vP5 += 32; vP6 += 32; vP7 += 32;
      GLD(vb[0], vP0, "0"); GLD(vb[1], vP1, "0"); GLD(vb[2], vP2, "0"); GLD(vb[3], vP3, "0");
      GLD(vb[4], vP4, "0"); GLD(vb[5], vP5, "0"); GLD(vb[6], vP6, "0"); GLD(vb[7], vP7, "0");
    }
  }

  // drain junk K loads before epilogue (they target kb regs that may be reallocated)
  WAITV(0);

  // ---- epilogue: normalize and store ----
#pragma unroll
  for (int r = 0; r < 4; ++r) {
    const float lr  = __shfl(lreg, (quad * 4 + r) << 2, 64);
    const float inv = 1.0f / lr;
    const long rowoff = base + (long)(q0w + quad * 4 + r) * 2048;
#pragma unroll
    for (int c = 0; c < 8; ++c)
      AO[rowoff + c * 16 + l15] = f2bf(flushv(o[c][r] * inv, 9999.f));
  }
}

// ================= diagnostic fill =================
__global__ __launch_bounds__(256) void fill_kernel(float* __restrict__ out, long n, float v)
{
  const long t = (long)blockIdx.x * 256 + threadIdx.x;
  if (t < n) out[t] = v;
}

// ================= launch =================
extern "C" void kernel_launch(void* const* d_in, const int* in_sizes, int n_in,
                              void* d_out, int out_size, void* d_ws, size_t ws_size,
                              hipStream_t stream)
{
  // Inputs fp32 (x, Wq, Wk, Wv, Wo); OUTPUT fp32 (reference dtype).
  const float* x  = (const float*)d_in[0];
  const float* Wq = (const float*)d_in[1];
  const float* Wk = (const float*)d_in[2];
  const float* Wv = (const float*)d_in[3];
  const float* Wo = (const float*)d_in[4];
  float* out = (float*)d_out;

  const long QSZ = (long)2 * 2048 * 2048;  // 8388608 elems

  // ws guard (needs 48 MB of bf16 scratch); sentinel 1111 localizes
  if (ws_size < (size_t)3 * QSZ * sizeof(u16)) {
    fill_kernel<<<(int)((QSZ + 255) / 256), 256, 0, stream>>>(out, QSZ, 1111.f);
    return;
  }

  u16* ws = (u16*)d_ws;
  u16* q  = ws;            // bf16 internal
  u16* k  = ws + QSZ;
  u16* v  = ws + 2 * QSZ;  // V^T: [2048 d][4096 tok]
  u16* ao = q;             // attention output in-place over q (partition-safe)

  // sentinels: QKV=7777, attention=9999, outproj=5555, ws=1111
  // Q,K projections: [4096 tok][2048 d]
  gemm_bt<true, true, false><<<dim3(16, 32, 2), 256, 0, stream>>>(
      x, Wq, Wk, Wk, q, k, k, 4096, 2048, 2048, 7777.f);
  // V^T = Wv @ x^T : C[d][tok] = sum_k Wv[d][k] x[tok][k]  -> [2048][4096]
  gemm_bt<true, true, false><<<dim3(32, 16, 1), 256, 0, stream>>>(
      Wv, x, x, x, v, v, v, 2048, 4096, 2048, 7777.f);
  rope_kernel<<<32768, 256, 0, stream>>>(q, k);
  attn_kernel<<<1024, 256, 0, stream>>>(q, k, v, ao);
  gemm_bt<false, true, true><<<dim3(16, 32, 1), 256, 0, stream>>>(
      ao, Wo, Wo, Wo, out, out, out, 4096, 2048, 2048, 5555.f);
}

// Round 5
// 540.703 us; speedup vs baseline: 1.3212x; 1.3212x over previous
//
#include <hip/hip_runtime.h>

typedef unsigned short u16;
typedef __attribute__((ext_vector_type(8))) short short8;
typedef __attribute__((ext_vector_type(4))) float f32x4;
typedef __attribute__((ext_vector_type(4))) int i32x4;

// ---------- bf16 helpers (RNE) ----------
__device__ __forceinline__ float bf2f(u16 u) {
  union { unsigned u; float f; } v; v.u = ((unsigned)u) << 16; return v.f;
}
__device__ __forceinline__ u16 f2bf(float f) {
  union { float f; unsigned u; } v; v.f = f;
  unsigned r = (v.u + 0x7FFFu + ((v.u >> 16) & 1u)) >> 16;
  return (u16)r;
}
__device__ __forceinline__ float flushv(float t, float sentinel) {
  if (t != t || fabsf(t) > 3.0e38f) return sentinel;
  return t;
}
// load 8 fp32 and convert to bf16x8
__device__ __forceinline__ short8 ld8f(const float* p) {
  const float4 f0 = *(const float4*)p;
  const float4 f1 = *(const float4*)(p + 4);
  short8 r;
  r[0] = (short)f2bf(f0.x); r[1] = (short)f2bf(f0.y);
  r[2] = (short)f2bf(f0.z); r[3] = (short)f2bf(f0.w);
  r[4] = (short)f2bf(f1.x); r[5] = (short)f2bf(f1.y);
  r[6] = (short)f2bf(f1.z); r[7] = (short)f2bf(f1.w);
  return r;
}

// async global->LDS, 16B per lane; LDS dest = wave-uniform base + lane*16 (linear)
__device__ __forceinline__ void gl16(const u16* g, u16* l) {
  __builtin_amdgcn_global_load_lds(
      (const __attribute__((address_space(1))) void*)g,
      (__attribute__((address_space(3))) void*)l, 16, 0, 0);
}

// ================= GEMM: C[M,N] = A[M,K] @ W[N,K]^T =================
// AF/WF: operand is fp32 in global (convert to bf16 at staging). OF: output fp32.
// m93 structure: 128x128 tile, BK=32, VGPR staging, 2 barriers, 16x16x32 MFMA.
template <bool AF, bool WF, bool OF>
__global__ __launch_bounds__(256) void gemm_bt(
    const void* __restrict__ Ap,
    const void* __restrict__ Wp0, const void* __restrict__ Wp1, const void* __restrict__ Wp2,
    void* __restrict__ O0, void* __restrict__ O1, void* __restrict__ O2,
    int M, int N, int K, float sentinel)
{
  __shared__ __align__(16) u16 As[128 * 32];
  __shared__ __align__(16) u16 Bs[128 * 32];

  const void* Wp; void* O;
  if (blockIdx.z == 0)      { Wp = Wp0; O = O0; }
  else if (blockIdx.z == 1) { Wp = Wp1; O = O1; }
  else                      { Wp = Wp2; O = O2; }

  const float* Af = (const float*)Ap;  const u16* Ab = (const u16*)Ap;
  const float* Wf = (const float*)Wp;  const u16* Wb = (const u16*)Wp;

  const int tid  = threadIdx.x;
  const int wave = tid >> 6;
  const int lane = tid & 63;
  const int quad = lane >> 4;
  const int l15  = lane & 15;

  const int m0 = blockIdx.y * 128;
  const int n0 = blockIdx.x * 128;
  const int wm = (wave >> 1) * 64;
  const int wn = (wave & 1) * 64;

  const int e0 = wave * 1024 + lane * 8;
  const int e1 = e0 + 512;
  const int r0 = e0 >> 5, c0 = e0 & 31;
  const int r1 = e1 >> 5, c1 = e1 & 31;

  const long aoff0 = (long)(m0 + r0) * K + c0;
  const long aoff1 = (long)(m0 + r1) * K + c1;
  const long boff0 = (long)(n0 + r0) * K + c0;
  const long boff1 = (long)(n0 + r1) * K + c1;

  const f32x4 zero = {0.f, 0.f, 0.f, 0.f};
  f32x4 acc[4][4];
#pragma unroll
  for (int i = 0; i < 4; ++i)
#pragma unroll
    for (int j = 0; j < 4; ++j) acc[i][j] = zero;

  for (int k0 = 0; k0 < K; k0 += 32) {
    short8 a0, a1, b0, b1;
    if constexpr (AF) {
      a0 = ld8f(Af + aoff0 + k0);
      a1 = ld8f(Af + aoff1 + k0);
    } else {
      a0 = *(const short8*)(Ab + aoff0 + k0);
      a1 = *(const short8*)(Ab + aoff1 + k0);
    }
    if constexpr (WF) {
      b0 = ld8f(Wf + boff0 + k0);
      b1 = ld8f(Wf + boff1 + k0);
    } else {
      b0 = *(const short8*)(Wb + boff0 + k0);
      b1 = *(const short8*)(Wb + boff1 + k0);
    }

    __syncthreads();
    *(short8*)&As[e0] = a0;
    *(short8*)&As[e1] = a1;
    *(short8*)&Bs[e0] = b0;
    *(short8*)&Bs[e1] = b1;
    __syncthreads();

    short8 af[4], bf[4];
#pragma unroll
    for (int i = 0; i < 4; ++i)
      af[i] = *(const short8*)&As[(wm + i * 16 + l15) * 32 + quad * 8];
#pragma unroll
    for (int j = 0; j < 4; ++j)
      bf[j] = *(const short8*)&Bs[(wn + j * 16 + l15) * 32 + quad * 8];
#pragma unroll
    for (int i = 0; i < 4; ++i)
#pragma unroll
      for (int j = 0; j < 4; ++j)
        acc[i][j] = __builtin_amdgcn_mfma_f32_16x16x32_bf16(af[i], bf[j], acc[i][j], 0, 0, 0);
  }

  // C/D layout: col = lane&15, row = quad*4 + reg (verified m89/m91)
#pragma unroll
  for (int i = 0; i < 4; ++i) {
    const int row0 = m0 + wm + i * 16 + quad * 4;
#pragma unroll
    for (int j = 0; j < 4; ++j) {
      const int col = n0 + wn + j * 16 + l15;
#pragma unroll
      for (int r = 0; r < 4; ++r) {
        const float val = flushv(acc[i][j][r], sentinel);
        if constexpr (OF)
          ((float*)O)[(long)(row0 + r) * N + col] = val;
        else
          ((u16*)O)[(long)(row0 + r) * N + col] = f2bf(val);
      }
    }
  }
}

// ================= RoPE (chunk-half), in-place on bf16 Q and K =================
__global__ __launch_bounds__(256) void rope_kernel(u16* __restrict__ Q, u16* __restrict__ K)
{
  int t = blockIdx.x * 256 + threadIdx.x;
  const int half = 2 * 2048 * 16 * 64;
  u16* P = Q;
  if (t >= half) { P = K; t -= half; }
  const int i = t & 63;
  const int s = (t >> 10) & 2047;
  const long off = ((long)(t >> 6) << 7) + i;

  const float inv_freq = __expf((float)i * -0.14391156831212787f);  // 10000^(-i/64)
  const float fr = (float)s * inv_freq;
  float sn, cs;
  __sincosf(fr, &sn, &cs);

  const float q1 = bf2f(P[off]);
  const float q2 = bf2f(P[off + 64]);
  P[off]      = f2bf(q1 * cs - q2 * sn);
  P[off + 64] = f2bf(q1 * sn + q2 * cs);
}

// ================= causal flash attention (LDS-staged, lockstep, 2-phase) =================
// Q,K: [b,s,h*128+d] bf16.  VT: [h*128+d][b*2048+s] bf16 (pre-transposed by gemm).
// R4 lesson: per-wave global K/V loads are request-rate-bound (16 lines/instr, 4x
// redundant across drifting waves) — identical across 3 schedule variants. Fix:
// stage K,V ONCE per block via global_load_lds (pre-swizzled global source, linear
// LDS dest — rule #21), double-buffered, one __syncthreads per tile (stage jb+1
// issued before compute jb covers its latency). Swapped QK^T (T12): mfma(K,Q)
// makes S^T register-resident (key=quad*4+r, q=l15) — no S LDS buffer at all.
// LDS 32KB, 4 blocks/CU (whole grid co-resident). AO may alias Q (own rows only).
__global__ __launch_bounds__(256, 4) void attn_kernel(
    const u16* __restrict__ Q, const u16* __restrict__ K,
    const u16* __restrict__ VT, u16* __restrict__ AO)
{
  __shared__ __align__(16) u16 Kb[2][4096];  // [32 key][128 d], unit^=(row&7) swizzle
  __shared__ __align__(16) u16 Vb[2][4096];  // [128 d][32 tok], unit^=((row>>1)&3)

  const int tid  = threadIdx.x;
  const int wave = tid >> 6;
  const int lane = tid & 63;
  const int quad = lane >> 4;
  const int l15  = lane & 15;

  // XCD-grouped, per-CU qb-balanced mapping: blocks {hi=0..3} of one lane-slot get
  // qb {g,31-g,g,31-g} -> equal per-CU work; bh = (xcd<<2)|hi bijective.
  const int lin = blockIdx.x;                 // 0..1023
  const int xcd = lin & 7;
  const int hi  = lin >> 8;                   // 0..3
  const int g   = (lin >> 3) & 31;            // 0..31
  const int qb  = (hi & 1) ? (31 - g) : g;
  const int bh  = (xcd << 2) | hi;
  const int b   = bh >> 4;
  const int h   = bh & 15;

  const long base = (long)b * 2048 * 2048 + (long)h * 128;
  const long vtb  = (long)h * 128 * 4096 + (long)b * 2048;
  const int q0w = qb * 64 + wave * 16;
  const int qi  = q0w + l15;                  // this lane's q row (T12 layout)

  const u16* Kp0 = K + base;
  const u16* Vp0 = VT + vtb;

  // stage one 32-key tile (K 8KB + V 8KB) into buffer bs; global source is
  // pre-swizzled so the linear LDS write lands in swizzled layout (m173 pattern)
  auto STAGE = [&](int bs, int jb) {
#pragma unroll
    for (int gi = 0; gi < 2; ++gi) {
      const int slot = wave * 2 + gi;
      {  // K: 4 rows x 16 units of 16B per wave-instr
        const int row = slot * 4 + (lane >> 4);
        const int su  = lane & 15;
        gl16(Kp0 + (long)(jb * 32 + row) * 2048 + ((su ^ (row & 7)) << 3),
             &Kb[bs][slot * 512]);
      }
      {  // V: 16 rows x 4 units of 16B per wave-instr
        const int row = slot * 16 + (lane >> 2);
        const int su  = lane & 3;
        gl16(Vp0 + (long)row * 4096 + jb * 32 + ((su ^ ((row >> 1) & 3)) << 3),
             &Vb[bs][slot * 512]);
      }
    }
  };

  // Q fragments (one-time, plain loads)
  short8 qa[4];
#pragma unroll
  for (int c = 0; c < 4; ++c)
    qa[c] = *(const short8*)&Q[base + (long)(q0w + l15) * 2048 + c * 32 + quad * 8];

  const f32x4 zero = {0.f, 0.f, 0.f, 0.f};
  f32x4 o[8];
#pragma unroll
  for (int c = 0; c < 8; ++c) o[c] = zero;

  float mreg = -1e30f, lreg = 0.f;           // running max / denom for q = qi
  const float scale = 0.08838834764831845f;  // 1/sqrt(128)

  const int njb_blk = qb * 2 + 2;            // block-uniform tile count
  const int njb_w   = qb * 2 + 1 + (wave >> 1);  // waves 0,1 skip fully-masked last

  STAGE(0, 0);
  __syncthreads();

  const int xorK = l15 & 7;
  const int xorV = (l15 >> 1) & 3;

  int cur = 0;
  for (int jb = 0; jb < njb_blk; ++jb) {
    if (jb + 1 < njb_blk) STAGE(cur ^ 1, jb + 1);   // covered by compute below

    if (jb < njb_w) {
      const int j0 = jb * 32;

      // ---- swapped QK^T: S^T[key][q] in registers ----
      f32x4 s0T = zero, s1T = zero;
#pragma unroll
      for (int c = 0; c < 4; ++c) {
        const short8 kA = *(const short8*)&Kb[cur][l15 * 128 + (((c * 4 + quad) ^ xorK) << 3)];
        const short8 kB2 = *(const short8*)&Kb[cur][(l15 + 16) * 128 + (((c * 4 + quad) ^ xorK) << 3)];
        s0T = __builtin_amdgcn_mfma_f32_16x16x32_bf16(kA, qa[c], s0T, 0, 0, 0);
        s1T = __builtin_amdgcn_mfma_f32_16x16x32_bf16(kB2, qa[c], s1T, 0, 0, 0);
      }

      // ---- online softmax, all in registers (lane owns q=qi, keys quad*4+r,+16) ----
      float sv0[4], sv1[4];
      float pmax = -1e30f;
      if (j0 + 31 > q0w) {                   // wave-uniform: diagonal tile only
#pragma unroll
        for (int r = 0; r < 4; ++r) {
          const int k0i = j0 + quad * 4 + r;
          float s0 = s0T[r] * scale; if (k0i > qi)      s0 = -1e30f;
          float s1 = s1T[r] * scale; if (k0i + 16 > qi) s1 = -1e30f;
          sv0[r] = s0; sv1[r] = s1;
          pmax = fmaxf(pmax, fmaxf(s0, s1));
        }
      } else {
#pragma unroll
        for (int r = 0; r < 4; ++r) {
          sv0[r] = s0T[r] * scale;
          sv1[r] = s1T[r] * scale;
          pmax = fmaxf(pmax, fmaxf(sv0[r], sv1[r]));
        }
      }
      pmax = fmaxf(pmax, __shfl_xor(pmax, 16, 64));
      pmax = fmaxf(pmax, __shfl_xor(pmax, 32, 64));
      const float mprev = mreg;
      const float mnew  = fmaxf(mprev, pmax);
      const float alpha = __expf(mprev - mnew);  // first tile: 0, o==0 anyway
      float psum = 0.f;
#pragma unroll
      for (int r = 0; r < 4; ++r) {
        sv0[r] = __expf(sv0[r] - mnew);
        sv1[r] = __expf(sv1[r] - mnew);
        psum += sv0[r] + sv1[r];
      }
      psum += __shfl_xor(psum, 16, 64);
      psum += __shfl_xor(psum, 32, 64);
      lreg = lreg * alpha + psum;
      mreg = mnew;

      // ---- P -> A-fragment: 4 cvt_pk + 8 shuffles + 4 selects (no LDS) ----
      int w0, w1, w2, w3;
      asm("v_cvt_pk_bf16_f32 %0, %1, %2" : "=v"(w0) : "v"(sv0[0]), "v"(sv0[1]));
      asm("v_cvt_pk_bf16_f32 %0, %1, %2" : "=v"(w1) : "v"(sv0[2]), "v"(sv0[3]));
      asm("v_cvt_pk_bf16_f32 %0, %1, %2" : "=v"(w2) : "v"(sv1[0]), "v"(sv1[1]));
      asm("v_cvt_pk_bf16_f32 %0, %1, %2" : "=v"(w3) : "v"(sv1[2]), "v"(sv1[3]));
      const int srcA = l15 + ((quad & 1) << 5);   // lane holding key-pairs 2q (lo)
      const int srcB = srcA + 16;                 // and the next quad group
      const int a0 = __shfl(w0, srcA, 64), a1 = __shfl(w1, srcA, 64);
      const int a2 = __shfl(w0, srcB, 64), a3 = __shfl(w1, srcB, 64);
      const int h0 = __shfl(w2, srcA, 64), h1 = __shfl(w3, srcA, 64);
      const int h2 = __shfl(w2, srcB, 64), h3 = __shfl(w3, srcB, 64);
      const bool hiq = quad >= 2;                 // keys 16..31 half
      i32x4 pt;
      pt[0] = hiq ? h0 : a0;
      pt[1] = hiq ? h1 : a1;
      pt[2] = hiq ? h2 : a2;
      pt[3] = hiq ? h3 : a3;
      const short8 pa = *(const short8*)&pt;

      // ---- rescale O by alpha of rows quad*4+r ----
      float av[4];
#pragma unroll
      for (int r = 0; r < 4; ++r) av[r] = __shfl(alpha, quad * 4 + r, 64);
#pragma unroll
      for (int c = 0; c < 8; ++c) {
        o[c][0] *= av[0]; o[c][1] *= av[1]; o[c][2] *= av[2]; o[c][3] *= av[3];
      }

      // ---- PV from swizzled LDS V ----
#pragma unroll
      for (int c = 0; c < 8; ++c) {
        const short8 vf = *(const short8*)&Vb[cur][(c * 16 + l15) * 32 + ((quad ^ xorV) << 3)];
        o[c] = __builtin_amdgcn_mfma_f32_16x16x32_bf16(pa, vf, o[c], 0, 0, 0);
      }
    }

    __syncthreads();   // drains vmcnt (stage jb+1 complete) + all waves done with cur
    cur ^= 1;
  }

  // ---- epilogue: normalize and store ----
#pragma unroll
  for (int r = 0; r < 4; ++r) {
    const float lr  = __shfl(lreg, quad * 4 + r, 64);
    const float inv = 1.0f / lr;
    const long rowoff = base + (long)(q0w + quad * 4 + r) * 2048;
#pragma unroll
    for (int c = 0; c < 8; ++c)
      AO[rowoff + c * 16 + l15] = f2bf(flushv(o[c][r] * inv, 9999.f));
  }
}

// ================= diagnostic fill =================
__global__ __launch_bounds__(256) void fill_kernel(float* __restrict__ out, long n, float v)
{
  const long t = (long)blockIdx.x * 256 + threadIdx.x;
  if (t < n) out[t] = v;
}

// ================= launch =================
extern "C" void kernel_launch(void* const* d_in, const int* in_sizes, int n_in,
                              void* d_out, int out_size, void* d_ws, size_t ws_size,
                              hipStream_t stream)
{
  // Inputs fp32 (x, Wq, Wk, Wv, Wo); OUTPUT fp32 (reference dtype).
  const float* x  = (const float*)d_in[0];
  const float* Wq = (const float*)d_in[1];
  const float* Wk = (const float*)d_in[2];
  const float* Wv = (const float*)d_in[3];
  const float* Wo = (const float*)d_in[4];
  float* out = (float*)d_out;

  const long QSZ = (long)2 * 2048 * 2048;  // 8388608 elems

  // ws guard (needs 48 MB of bf16 scratch); sentinel 1111 localizes
  if (ws_size < (size_t)3 * QSZ * sizeof(u16)) {
    fill_kernel<<<(int)((QSZ + 255) / 256), 256, 0, stream>>>(out, QSZ, 1111.f);
    return;
  }

  u16* ws = (u16*)d_ws;
  u16* q  = ws;            // bf16 internal
  u16* k  = ws + QSZ;
  u16* v  = ws + 2 * QSZ;  // V^T: [2048 d][4096 tok]
  u16* ao = q;             // attention output in-place over q (partition-safe)

  // sentinels: QKV=7777, attention=9999, outproj=5555, ws=1111
  // Q,K projections: [4096 tok][2048 d]
  gemm_bt<true, true, false><<<dim3(16, 32, 2), 256, 0, stream>>>(
      x, Wq, Wk, Wk, q, k, k, 4096, 2048, 2048, 7777.f);
  // V^T = Wv @ x^T : C[d][tok] = sum_k Wv[d][k] x[tok][k]  -> [2048][4096]
  gemm_bt<true, true, false><<<dim3(32, 16, 1), 256, 0, stream>>>(
      Wv, x, x, x, v, v, v, 2048, 4096, 2048, 7777.f);
  rope_kernel<<<32768, 256, 0, stream>>>(q, k);
  attn_kernel<<<1024, 256, 0, stream>>>(q, k, v, ao);
  gemm_bt<false, true, true><<<dim3(16, 32, 1), 256, 0, stream>>>(
      ao, Wo, Wo, Wo, out, out, out, 4096, 2048, 2048, 5555.f);
}

// Round 6
// 455.336 us; speedup vs baseline: 1.5690x; 1.1875x over previous
//
#include <hip/hip_runtime.h>

typedef unsigned short u16;
typedef __attribute__((ext_vector_type(8))) short short8;
typedef __attribute__((ext_vector_type(4))) float f32x4;
typedef __attribute__((ext_vector_type(4))) int i32x4;

// ---------- bf16 helpers (RNE) ----------
__device__ __forceinline__ float bf2f(u16 u) {
  union { unsigned u; float f; } v; v.u = ((unsigned)u) << 16; return v.f;
}
__device__ __forceinline__ u16 f2bf(float f) {
  union { float f; unsigned u; } v; v.f = f;
  unsigned r = (v.u + 0x7FFFu + ((v.u >> 16) & 1u)) >> 16;
  return (u16)r;
}
__device__ __forceinline__ float flushv(float t, float sentinel) {
  if (t != t || fabsf(t) > 3.0e38f) return sentinel;
  return t;
}
// load 8 fp32 and convert to bf16x8
__device__ __forceinline__ short8 ld8f(const float* p) {
  const float4 f0 = *(const float4*)p;
  const float4 f1 = *(const float4*)(p + 4);
  short8 r;
  r[0] = (short)f2bf(f0.x); r[1] = (short)f2bf(f0.y);
  r[2] = (short)f2bf(f0.z); r[3] = (short)f2bf(f0.w);
  r[4] = (short)f2bf(f1.x); r[5] = (short)f2bf(f1.y);
  r[6] = (short)f2bf(f1.z); r[7] = (short)f2bf(f1.w);
  return r;
}

// async global->LDS, 16B per lane; LDS dest = wave-uniform base + lane*16 (linear)
__device__ __forceinline__ void gl16(const u16* g, u16* l) {
  __builtin_amdgcn_global_load_lds(
      (const __attribute__((address_space(1))) void*)g,
      (__attribute__((address_space(3))) void*)l, 16, 0, 0);
}

// ================= fp32 -> bf16 conversion passes =================
__global__ __launch_bounds__(256) void cvt_kernel(
    const float* __restrict__ src, u16* __restrict__ dst, long n8)
{
  const long t = (long)blockIdx.x * 256 + threadIdx.x;
  if (t < n8) *(short8*)&dst[t * 8] = ld8f(src + t * 8);
}

// 4 equal-size tensors (2048x2048), 2048 blocks each
__global__ __launch_bounds__(256) void cvt4_kernel(
    const float* __restrict__ s0, const float* __restrict__ s1,
    const float* __restrict__ s2, const float* __restrict__ s3,
    u16* __restrict__ d0, u16* __restrict__ d1,
    u16* __restrict__ d2, u16* __restrict__ d3)
{
  const int which = blockIdx.x >> 11;
  const long t = (long)(blockIdx.x & 2047) * 256 + threadIdx.x;  // < 524288
  const float* s; u16* d;
  if (which == 0)      { s = s0; d = d0; }
  else if (which == 1) { s = s1; d = d1; }
  else if (which == 2) { s = s2; d = d2; }
  else                 { s = s3; d = d3; }
  *(short8*)&d[t * 8] = ld8f(s + t * 8);
}

// ================= m97-structure GEMM: C[M,N] = A[M,K] @ B[N,K]^T, bf16 in =================
// global_load_lds width-16 staging (no VGPR round-trip, no conversion VALU),
// 128x128 tile, BK=32, 2 barriers/K-step, 16x16x32 MFMA. OF: fp32 out else bf16.
template <bool OF>
__global__ __launch_bounds__(256) void gemm_lds(
    const u16* __restrict__ Ap,
    const u16* __restrict__ B0, const u16* __restrict__ B1,
    void* __restrict__ O0, void* __restrict__ O1,
    int M, int N, int K, float sentinel)
{
  __shared__ __align__(16) u16 As[128 * 32];
  __shared__ __align__(16) u16 Bs[128 * 32];

  const u16* Bp = (blockIdx.z == 0) ? B0 : B1;
  void* O       = (blockIdx.z == 0) ? O0 : O1;

  const int tid  = threadIdx.x;
  const int wave = tid >> 6;
  const int lane = tid & 63;
  const int quad = lane >> 4;
  const int l15  = lane & 15;

  const int m0 = blockIdx.y * 128;
  const int n0 = blockIdx.x * 128;
  const int wm = (wave >> 1) * 64;
  const int wn = (wave & 1) * 64;

  // staging geometry: slot = wave*2+gi covers 16 rows; lane>>2 = row-in-slot,
  // lane&3 = 16B unit within the 32-elem row. LDS linear: As[slot*512 + lane*8].
  const int srow = lane >> 2;
  const int scu  = lane & 3;
  const u16* Ag0 = Ap + (long)(m0 + wave * 32 + srow) * K + scu * 8;
  const u16* Ag1 = Ag0 + 16 * (long)K;
  const u16* Bg0 = Bp + (long)(n0 + wave * 32 + srow) * K + scu * 8;
  const u16* Bg1 = Bg0 + 16 * (long)K;
  u16* Al0 = &As[(wave * 2 + 0) * 512];
  u16* Al1 = &As[(wave * 2 + 1) * 512];
  u16* Bl0 = &Bs[(wave * 2 + 0) * 512];
  u16* Bl1 = &Bs[(wave * 2 + 1) * 512];

  const f32x4 zero = {0.f, 0.f, 0.f, 0.f};
  f32x4 acc[4][4];
#pragma unroll
  for (int i = 0; i < 4; ++i)
#pragma unroll
    for (int j = 0; j < 4; ++j) acc[i][j] = zero;

  for (int k0 = 0; k0 < K; k0 += 32) {
    __syncthreads();                 // prev compute done before LDS overwrite
    gl16(Ag0 + k0, Al0);
    gl16(Ag1 + k0, Al1);
    gl16(Bg0 + k0, Bl0);
    gl16(Bg1 + k0, Bl1);
    __syncthreads();                 // drains vmcnt: tiles resident

    short8 af[4], bf[4];
#pragma unroll
    for (int i = 0; i < 4; ++i)
      af[i] = *(const short8*)&As[(wm + i * 16 + l15) * 32 + quad * 8];
#pragma unroll
    for (int j = 0; j < 4; ++j)
      bf[j] = *(const short8*)&Bs[(wn + j * 16 + l15) * 32 + quad * 8];
#pragma unroll
    for (int i = 0; i < 4; ++i)
#pragma unroll
      for (int j = 0; j < 4; ++j)
        acc[i][j] = __builtin_amdgcn_mfma_f32_16x16x32_bf16(af[i], bf[j], acc[i][j], 0, 0, 0);
  }

  // C/D layout: col = lane&15, row = quad*4 + reg (verified m89/m91)
#pragma unroll
  for (int i = 0; i < 4; ++i) {
    const int row0 = m0 + wm + i * 16 + quad * 4;
#pragma unroll
    for (int j = 0; j < 4; ++j) {
      const int col = n0 + wn + j * 16 + l15;
#pragma unroll
      for (int r = 0; r < 4; ++r) {
        const float val = flushv(acc[i][j][r], sentinel);
        if constexpr (OF)
          ((float*)O)[(long)(row0 + r) * N + col] = val;
        else
          ((u16*)O)[(long)(row0 + r) * N + col] = f2bf(val);
      }
    }
  }
}

// ================= legacy GEMM (fp32-staging) — fallback path only =================
template <bool AF, bool WF, bool OF>
__global__ __launch_bounds__(256) void gemm_bt(
    const void* __restrict__ Ap,
    const void* __restrict__ Wp0, const void* __restrict__ Wp1, const void* __restrict__ Wp2,
    void* __restrict__ O0, void* __restrict__ O1, void* __restrict__ O2,
    int M, int N, int K, float sentinel)
{
  __shared__ __align__(16) u16 As[128 * 32];
  __shared__ __align__(16) u16 Bs[128 * 32];

  const void* Wp; void* O;
  if (blockIdx.z == 0)      { Wp = Wp0; O = O0; }
  else if (blockIdx.z == 1) { Wp = Wp1; O = O1; }
  else                      { Wp = Wp2; O = O2; }

  const float* Af = (const float*)Ap;  const u16* Ab = (const u16*)Ap;
  const float* Wf = (const float*)Wp;  const u16* Wb = (const u16*)Wp;

  const int tid  = threadIdx.x;
  const int wave = tid >> 6;
  const int lane = tid & 63;
  const int quad = lane >> 4;
  const int l15  = lane & 15;

  const int m0 = blockIdx.y * 128;
  const int n0 = blockIdx.x * 128;
  const int wm = (wave >> 1) * 64;
  const int wn = (wave & 1) * 64;

  const int e0 = wave * 1024 + lane * 8;
  const int e1 = e0 + 512;
  const int r0 = e0 >> 5, c0 = e0 & 31;
  const int r1 = e1 >> 5, c1 = e1 & 31;

  const long aoff0 = (long)(m0 + r0) * K + c0;
  const long aoff1 = (long)(m0 + r1) * K + c1;
  const long boff0 = (long)(n0 + r0) * K + c0;
  const long boff1 = (long)(n0 + r1) * K + c1;

  const f32x4 zero = {0.f, 0.f, 0.f, 0.f};
  f32x4 acc[4][4];
#pragma unroll
  for (int i = 0; i < 4; ++i)
#pragma unroll
    for (int j = 0; j < 4; ++j) acc[i][j] = zero;

  for (int k0 = 0; k0 < K; k0 += 32) {
    short8 a0, a1, b0, b1;
    if constexpr (AF) {
      a0 = ld8f(Af + aoff0 + k0);
      a1 = ld8f(Af + aoff1 + k0);
    } else {
      a0 = *(const short8*)(Ab + aoff0 + k0);
      a1 = *(const short8*)(Ab + aoff1 + k0);
    }
    if constexpr (WF) {
      b0 = ld8f(Wf + boff0 + k0);
      b1 = ld8f(Wf + boff1 + k0);
    } else {
      b0 = *(const short8*)(Wb + boff0 + k0);
      b1 = *(const short8*)(Wb + boff1 + k0);
    }

    __syncthreads();
    *(short8*)&As[e0] = a0;
    *(short8*)&As[e1] = a1;
    *(short8*)&Bs[e0] = b0;
    *(short8*)&Bs[e1] = b1;
    __syncthreads();

    short8 af[4], bf[4];
#pragma unroll
    for (int i = 0; i < 4; ++i)
      af[i] = *(const short8*)&As[(wm + i * 16 + l15) * 32 + quad * 8];
#pragma unroll
    for (int j = 0; j < 4; ++j)
      bf[j] = *(const short8*)&Bs[(wn + j * 16 + l15) * 32 + quad * 8];
#pragma unroll
    for (int i = 0; i < 4; ++i)
#pragma unroll
      for (int j = 0; j < 4; ++j)
        acc[i][j] = __builtin_amdgcn_mfma_f32_16x16x32_bf16(af[i], bf[j], acc[i][j], 0, 0, 0);
  }

#pragma unroll
  for (int i = 0; i < 4; ++i) {
    const int row0 = m0 + wm + i * 16 + quad * 4;
#pragma unroll
    for (int j = 0; j < 4; ++j) {
      const int col = n0 + wn + j * 16 + l15;
#pragma unroll
      for (int r = 0; r < 4; ++r) {
        const float val = flushv(acc[i][j][r], sentinel);
        if constexpr (OF)
          ((float*)O)[(long)(row0 + r) * N + col] = val;
        else
          ((u16*)O)[(long)(row0 + r) * N + col] = f2bf(val);
      }
    }
  }
}

// ================= RoPE (chunk-half), in-place on bf16 Q and K =================
__global__ __launch_bounds__(256) void rope_kernel(u16* __restrict__ Q, u16* __restrict__ K)
{
  int t = blockIdx.x * 256 + threadIdx.x;
  const int half = 2 * 2048 * 16 * 64;
  u16* P = Q;
  if (t >= half) { P = K; t -= half; }
  const int i = t & 63;
  const int s = (t >> 10) & 2047;
  const long off = ((long)(t >> 6) << 7) + i;

  const float inv_freq = __expf((float)i * -0.14391156831212787f);  // 10000^(-i/64)
  const float fr = (float)s * inv_freq;
  float sn, cs;
  __sincosf(fr, &sn, &cs);

  const float q1 = bf2f(P[off]);
  const float q2 = bf2f(P[off + 64]);
  P[off]      = f2bf(q1 * cs - q2 * sn);
  P[off + 64] = f2bf(q1 * sn + q2 * cs);
}

// ================= causal flash attention (LDS-staged, lockstep, 2-phase) =================
// R5-verified: stage K,V once per block via global_load_lds (pre-swizzled global
// source, linear LDS dest), double-buffered, 1 barrier/tile; swapped QK^T keeps
// S^T in registers; 4 blocks/CU, whole grid co-resident. AO may alias Q.
__global__ __launch_bounds__(256, 4) void attn_kernel(
    const u16* __restrict__ Q, const u16* __restrict__ K,
    const u16* __restrict__ VT, u16* __restrict__ AO)
{
  __shared__ __align__(16) u16 Kb[2][4096];  // [32 key][128 d], unit^=(row&7) swizzle
  __shared__ __align__(16) u16 Vb[2][4096];  // [128 d][32 tok], unit^=((row>>1)&3)

  const int tid  = threadIdx.x;
  const int wave = tid >> 6;
  const int lane = tid & 63;
  const int quad = lane >> 4;
  const int l15  = lane & 15;

  const int lin = blockIdx.x;                 // 0..1023
  const int xcd = lin & 7;
  const int hi  = lin >> 8;                   // 0..3
  const int g   = (lin >> 3) & 31;            // 0..31
  const int qb  = (hi & 1) ? (31 - g) : g;
  const int bh  = (xcd << 2) | hi;
  const int b   = bh >> 4;
  const int h   = bh & 15;

  const long base = (long)b * 2048 * 2048 + (long)h * 128;
  const long vtb  = (long)h * 128 * 4096 + (long)b * 2048;
  const int q0w = qb * 64 + wave * 16;
  const int qi  = q0w + l15;

  const u16* Kp0 = K + base;
  const u16* Vp0 = VT + vtb;

  auto STAGE = [&](int bs, int jb) {
#pragma unroll
    for (int gi = 0; gi < 2; ++gi) {
      const int slot = wave * 2 + gi;
      {
        const int row = slot * 4 + (lane >> 4);
        const int su  = lane & 15;
        gl16(Kp0 + (long)(jb * 32 + row) * 2048 + ((su ^ (row & 7)) << 3),
             &Kb[bs][slot * 512]);
      }
      {
        const int row = slot * 16 + (lane >> 2);
        const int su  = lane & 3;
        gl16(Vp0 + (long)row * 4096 + jb * 32 + ((su ^ ((row >> 1) & 3)) << 3),
             &Vb[bs][slot * 512]);
      }
    }
  };

  short8 qa[4];
#pragma unroll
  for (int c = 0; c < 4; ++c)
    qa[c] = *(const short8*)&Q[base + (long)(q0w + l15) * 2048 + c * 32 + quad * 8];

  const f32x4 zero = {0.f, 0.f, 0.f, 0.f};
  f32x4 o[8];
#pragma unroll
  for (int c = 0; c < 8; ++c) o[c] = zero;

  float mreg = -1e30f, lreg = 0.f;
  const float scale = 0.08838834764831845f;  // 1/sqrt(128)

  const int njb_blk = qb * 2 + 2;
  const int njb_w   = qb * 2 + 1 + (wave >> 1);

  STAGE(0, 0);
  __syncthreads();

  const int xorK = l15 & 7;
  const int xorV = (l15 >> 1) & 3;

  int cur = 0;
  for (int jb = 0; jb < njb_blk; ++jb) {
    if (jb + 1 < njb_blk) STAGE(cur ^ 1, jb + 1);

    if (jb < njb_w) {
      const int j0 = jb * 32;

      f32x4 s0T = zero, s1T = zero;
#pragma unroll
      for (int c = 0; c < 4; ++c) {
        const short8 kA = *(const short8*)&Kb[cur][l15 * 128 + (((c * 4 + quad) ^ xorK) << 3)];
        const short8 kB2 = *(const short8*)&Kb[cur][(l15 + 16) * 128 + (((c * 4 + quad) ^ xorK) << 3)];
        s0T = __builtin_amdgcn_mfma_f32_16x16x32_bf16(kA, qa[c], s0T, 0, 0, 0);
        s1T = __builtin_amdgcn_mfma_f32_16x16x32_bf16(kB2, qa[c], s1T, 0, 0, 0);
      }

      float sv0[4], sv1[4];
      float pmax = -1e30f;
      if (j0 + 31 > q0w) {
#pragma unroll
        for (int r = 0; r < 4; ++r) {
          const int k0i = j0 + quad * 4 + r;
          float s0 = s0T[r] * scale; if (k0i > qi)      s0 = -1e30f;
          float s1 = s1T[r] * scale; if (k0i + 16 > qi) s1 = -1e30f;
          sv0[r] = s0; sv1[r] = s1;
          pmax = fmaxf(pmax, fmaxf(s0, s1));
        }
      } else {
#pragma unroll
        for (int r = 0; r < 4; ++r) {
          sv0[r] = s0T[r] * scale;
          sv1[r] = s1T[r] * scale;
          pmax = fmaxf(pmax, fmaxf(sv0[r], sv1[r]));
        }
      }
      pmax = fmaxf(pmax, __shfl_xor(pmax, 16, 64));
      pmax = fmaxf(pmax, __shfl_xor(pmax, 32, 64));
      const float mprev = mreg;
      const float mnew  = fmaxf(mprev, pmax);
      const float alpha = __expf(mprev - mnew);
      float psum = 0.f;
#pragma unroll
      for (int r = 0; r < 4; ++r) {
        sv0[r] = __expf(sv0[r] - mnew);
        sv1[r] = __expf(sv1[r] - mnew);
        psum += sv0[r] + sv1[r];
      }
      psum += __shfl_xor(psum, 16, 64);
      psum += __shfl_xor(psum, 32, 64);
      lreg = lreg * alpha + psum;
      mreg = mnew;

      int w0, w1, w2, w3;
      asm("v_cvt_pk_bf16_f32 %0, %1, %2" : "=v"(w0) : "v"(sv0[0]), "v"(sv0[1]));
      asm("v_cvt_pk_bf16_f32 %0, %1, %2" : "=v"(w1) : "v"(sv0[2]), "v"(sv0[3]));
      asm("v_cvt_pk_bf16_f32 %0, %1, %2" : "=v"(w2) : "v"(sv1[0]), "v"(sv1[1]));
      asm("v_cvt_pk_bf16_f32 %0, %1, %2" : "=v"(w3) : "v"(sv1[2]), "v"(sv1[3]));
      const int srcA = l15 + ((quad & 1) << 5);
      const int srcB = srcA + 16;
      const int a0 = __shfl(w0, srcA, 64), a1 = __shfl(w1, srcA, 64);
      const int a2 = __shfl(w0, srcB, 64), a3 = __shfl(w1, srcB, 64);
      const int h0 = __shfl(w2, srcA, 64), h1 = __shfl(w3, srcA, 64);
      const int h2 = __shfl(w2, srcB, 64), h3 = __shfl(w3, srcB, 64);
      const bool hiq = quad >= 2;
      i32x4 pt;
      pt[0] = hiq ? h0 : a0;
      pt[1] = hiq ? h1 : a1;
      pt[2] = hiq ? h2 : a2;
      pt[3] = hiq ? h3 : a3;
      const short8 pa = *(const short8*)&pt;

      float av[4];
#pragma unroll
      for (int r = 0; r < 4; ++r) av[r] = __shfl(alpha, quad * 4 + r, 64);
#pragma unroll
      for (int c = 0; c < 8; ++c) {
        o[c][0] *= av[0]; o[c][1] *= av[1]; o[c][2] *= av[2]; o[c][3] *= av[3];
      }

#pragma unroll
      for (int c = 0; c < 8; ++c) {
        const short8 vf = *(const short8*)&Vb[cur][(c * 16 + l15) * 32 + ((quad ^ xorV) << 3)];
        o[c] = __builtin_amdgcn_mfma_f32_16x16x32_bf16(pa, vf, o[c], 0, 0, 0);
      }
    }

    __syncthreads();
    cur ^= 1;
  }

#pragma unroll
  for (int r = 0; r < 4; ++r) {
    const float lr  = __shfl(lreg, quad * 4 + r, 64);
    const float inv = 1.0f / lr;
    const long rowoff = base + (long)(q0w + quad * 4 + r) * 2048;
#pragma unroll
    for (int c = 0; c < 8; ++c)
      AO[rowoff + c * 16 + l15] = f2bf(flushv(o[c][r] * inv, 9999.f));
  }
}

// ================= diagnostic fill =================
__global__ __launch_bounds__(256) void fill_kernel(float* __restrict__ out, long n, float v)
{
  const long t = (long)blockIdx.x * 256 + threadIdx.x;
  if (t < n) out[t] = v;
}

// ================= launch =================
extern "C" void kernel_launch(void* const* d_in, const int* in_sizes, int n_in,
                              void* d_out, int out_size, void* d_ws, size_t ws_size,
                              hipStream_t stream)
{
  // Inputs fp32 (x, Wq, Wk, Wv, Wo); OUTPUT fp32 (reference dtype).
  const float* x  = (const float*)d_in[0];
  const float* Wq = (const float*)d_in[1];
  const float* Wk = (const float*)d_in[2];
  const float* Wv = (const float*)d_in[3];
  const float* Wo = (const float*)d_in[4];
  float* out = (float*)d_out;

  const long QSZ = (long)2 * 2048 * 2048;  // 8388608 elems
  const long WSZ = QSZ / 2;                // 2048*2048 weight elems

  u16* ws = (u16*)d_ws;
  u16* q  = ws;            // bf16 internal
  u16* k  = ws + QSZ;
  u16* v  = ws + 2 * QSZ;  // V^T: [2048 d][4096 tok]
  u16* ao = q;             // attention output in-place over q (partition-safe)

  if (ws_size >= (size_t)6 * QSZ * sizeof(u16)) {
    // ---- fast path: pre-convert to bf16 + global_load_lds GEMMs (m97 structure) ----
    u16* xb  = ws + 3 * QSZ;        // x as bf16 [4096][2048]
    u16* wqb = ws + 4 * QSZ;
    u16* wkb = wqb + WSZ;
    u16* wvb = wqb + 2 * WSZ;
    u16* wob = wqb + 3 * WSZ;

    cvt_kernel<<<4096, 256, 0, stream>>>(x, xb, QSZ / 8);
    cvt4_kernel<<<8192, 256, 0, stream>>>(Wq, Wk, Wv, Wo, wqb, wkb, wvb, wob);

    // Q,K projections: [4096 tok][2048 d]
    gemm_lds<false><<<dim3(16, 32, 2), 256, 0, stream>>>(
        xb, wqb, wkb, q, k, 4096, 2048, 2048, 7777.f);
    // V^T = Wv @ x^T : C[d][tok] -> [2048][4096]
    gemm_lds<false><<<dim3(32, 16, 1), 256, 0, stream>>>(
        wvb, xb, xb, v, v, 2048, 4096, 2048, 7777.f);
    rope_kernel<<<32768, 256, 0, stream>>>(q, k);
    attn_kernel<<<1024, 256, 0, stream>>>(q, k, v, ao);
    gemm_lds<true><<<dim3(16, 32, 1), 256, 0, stream>>>(
        ao, wob, wob, out, out, 4096, 2048, 2048, 5555.f);
    return;
  }

  // ---- fallback: R5 path (fp32-staging GEMMs), needs 48 MB ----
  if (ws_size < (size_t)3 * QSZ * sizeof(u16)) {
    fill_kernel<<<(int)((QSZ + 255) / 256), 256, 0, stream>>>(out, QSZ, 1111.f);
    return;
  }

  gemm_bt<true, true, false><<<dim3(16, 32, 2), 256, 0, stream>>>(
      x, Wq, Wk, Wk, q, k, k, 4096, 2048, 2048, 7777.f);
  gemm_bt<true, true, false><<<dim3(32, 16, 1), 256, 0, stream>>>(
      Wv, x, x, x, v, v, v, 2048, 4096, 2048, 7777.f);
  rope_kernel<<<32768, 256, 0, stream>>>(q, k);
  attn_kernel<<<1024, 256, 0, stream>>>(q, k, v, ao);
  gemm_bt<false, true, true><<<dim3(16, 32, 1), 256, 0, stream>>>(
      ao, Wo, Wo, Wo, out, out, out, 4096, 2048, 2048, 5555.f);
}

// Round 7
// 422.125 us; speedup vs baseline: 1.6924x; 1.0787x over previous
//
#include <hip/hip_runtime.h>

typedef unsigned short u16;
typedef __attribute__((ext_vector_type(8))) short short8;
typedef __attribute__((ext_vector_type(4))) float f32x4;
typedef __attribute__((ext_vector_type(4))) int i32x4;

// ---------- bf16 helpers (RNE) ----------
__device__ __forceinline__ float bf2f(u16 u) {
  union { unsigned u; float f; } v; v.u = ((unsigned)u) << 16; return v.f;
}
__device__ __forceinline__ u16 f2bf(float f) {
  union { float f; unsigned u; } v; v.f = f;
  unsigned r = (v.u + 0x7FFFu + ((v.u >> 16) & 1u)) >> 16;
  return (u16)r;
}
__device__ __forceinline__ float flushv(float t, float sentinel) {
  if (t != t || fabsf(t) > 3.0e38f) return sentinel;
  return t;
}
// load 8 fp32 and convert to bf16x8
__device__ __forceinline__ short8 ld8f(const float* p) {
  const float4 f0 = *(const float4*)p;
  const float4 f1 = *(const float4*)(p + 4);
  short8 r;
  r[0] = (short)f2bf(f0.x); r[1] = (short)f2bf(f0.y);
  r[2] = (short)f2bf(f0.z); r[3] = (short)f2bf(f0.w);
  r[4] = (short)f2bf(f1.x); r[5] = (short)f2bf(f1.y);
  r[6] = (short)f2bf(f1.z); r[7] = (short)f2bf(f1.w);
  return r;
}

// async global->LDS, 16B per lane; LDS dest = wave-uniform base + lane*16 (linear)
__device__ __forceinline__ void gl16(const u16* g, u16* l) {
  __builtin_amdgcn_global_load_lds(
      (const __attribute__((address_space(1))) void*)g,
      (__attribute__((address_space(3))) void*)l, 16, 0, 0);
}

// ================= fp32 -> bf16 conversion (single pass, 5 tensors) =================
// blocks 0..8191: the four 2048x2048 weights (2048 blocks each)
// blocks 8192..12287: x (4096 blocks)
__global__ __launch_bounds__(256) void cvt_all(
    const float* __restrict__ x,
    const float* __restrict__ Wq, const float* __restrict__ Wk,
    const float* __restrict__ Wv, const float* __restrict__ Wo,
    u16* __restrict__ xb, u16* __restrict__ wqb, u16* __restrict__ wkb,
    u16* __restrict__ wvb, u16* __restrict__ wob)
{
  const int bid = blockIdx.x;
  const float* s; u16* d; long t;
  if (bid < 8192) {
    const int which = bid >> 11;
    t = (long)(bid & 2047) * 256 + threadIdx.x;
    if (which == 0)      { s = Wq; d = wqb; }
    else if (which == 1) { s = Wk; d = wkb; }
    else if (which == 2) { s = Wv; d = wvb; }
    else                 { s = Wo; d = wob; }
  } else {
    s = x; d = xb;
    t = (long)(bid - 8192) * 256 + threadIdx.x;
  }
  *(short8*)&d[t * 8] = ld8f(s + t * 8);
}

// ================= GEMM core: C[M,N] = A[M,K] @ B[N,K]^T, bf16 in, K=2048 =================
// T3 "minimum 2-phase": double-buffered LDS, STAGE(next) issued BEFORE compute(cur),
// ONE __syncthreads per K-step (its vmcnt(0)+lgkmcnt(0) drain orders both the RAW on
// the prefetched buffer and the WAR on the buffer being restaged). K-loop unrolled x2
// for static buffer indexing (rule #20). 128x128 tile, BK=32, 16x16x32 MFMA.
template <bool OF>
__device__ __forceinline__ void gemm_core(
    const u16* __restrict__ Ap, const u16* __restrict__ Bp,
    void* __restrict__ O, int m0, int n0, int N, float sentinel)
{
  __shared__ __align__(16) u16 As[2][128 * 32];
  __shared__ __align__(16) u16 Bs[2][128 * 32];
  constexpr int K = 2048;

  const int tid  = threadIdx.x;
  const int wave = tid >> 6;
  const int lane = tid & 63;
  const int quad = lane >> 4;
  const int l15  = lane & 15;

  const int wm = (wave >> 1) * 64;
  const int wn = (wave & 1) * 64;

  // staging geometry: slot = wave*2+gi covers 16 rows; lane>>2 = row-in-slot,
  // lane&3 = 16B unit within the 32-elem row. LDS linear: slot*512 + lane*8.
  const int srow = lane >> 2;
  const int scu  = lane & 3;
  const u16* Ag0 = Ap + (long)(m0 + wave * 32 + srow) * K + scu * 8;
  const u16* Ag1 = Ag0 + 16 * (long)K;
  const u16* Bg0 = Bp + (long)(n0 + wave * 32 + srow) * K + scu * 8;
  const u16* Bg1 = Bg0 + 16 * (long)K;
  const int sl0 = (wave * 2 + 0) * 512;
  const int sl1 = (wave * 2 + 1) * 512;

  const f32x4 zero = {0.f, 0.f, 0.f, 0.f};
  f32x4 acc[4][4];
#pragma unroll
  for (int i = 0; i < 4; ++i)
#pragma unroll
    for (int j = 0; j < 4; ++j) acc[i][j] = zero;

  // prologue stage (only stage with uncovered latency)
  gl16(Ag0, &As[0][sl0]); gl16(Ag1, &As[0][sl1]);
  gl16(Bg0, &Bs[0][sl0]); gl16(Bg1, &Bs[0][sl1]);
  __syncthreads();

#pragma unroll 1
  for (int k0 = 0; k0 < K; k0 += 64) {
    // ---- step A: prefetch buf1 (k0+32), compute buf0 ----
    gl16(Ag0 + k0 + 32, &As[1][sl0]); gl16(Ag1 + k0 + 32, &As[1][sl1]);
    gl16(Bg0 + k0 + 32, &Bs[1][sl0]); gl16(Bg1 + k0 + 32, &Bs[1][sl1]);
    {
      short8 af[4], bf[4];
#pragma unroll
      for (int i = 0; i < 4; ++i)
        af[i] = *(const short8*)&As[0][(wm + i * 16 + l15) * 32 + quad * 8];
#pragma unroll
      for (int j = 0; j < 4; ++j)
        bf[j] = *(const short8*)&Bs[0][(wn + j * 16 + l15) * 32 + quad * 8];
#pragma unroll
      for (int i = 0; i < 4; ++i)
#pragma unroll
        for (int j = 0; j < 4; ++j)
          acc[i][j] = __builtin_amdgcn_mfma_f32_16x16x32_bf16(af[i], bf[j], acc[i][j], 0, 0, 0);
    }
    __syncthreads();   // buf1 resident; all waves done reading buf0

    // ---- step B: prefetch buf0 (k0+64), compute buf1 ----
    if (k0 + 64 < K) {
      gl16(Ag0 + k0 + 64, &As[0][sl0]); gl16(Ag1 + k0 + 64, &As[0][sl1]);
      gl16(Bg0 + k0 + 64, &Bs[0][sl0]); gl16(Bg1 + k0 + 64, &Bs[0][sl1]);
    }
    {
      short8 af[4], bf[4];
#pragma unroll
      for (int i = 0; i < 4; ++i)
        af[i] = *(const short8*)&As[1][(wm + i * 16 + l15) * 32 + quad * 8];
#pragma unroll
      for (int j = 0; j < 4; ++j)
        bf[j] = *(const short8*)&Bs[1][(wn + j * 16 + l15) * 32 + quad * 8];
#pragma unroll
      for (int i = 0; i < 4; ++i)
#pragma unroll
        for (int j = 0; j < 4; ++j)
          acc[i][j] = __builtin_amdgcn_mfma_f32_16x16x32_bf16(af[i], bf[j], acc[i][j], 0, 0, 0);
    }
    __syncthreads();   // buf0 resident; all waves done reading buf1
  }

  // C/D layout: col = lane&15, row = quad*4 + reg (verified m89/m91)
#pragma unroll
  for (int i = 0; i < 4; ++i) {
    const int row0 = m0 + wm + i * 16 + quad * 4;
#pragma unroll
    for (int j = 0; j < 4; ++j) {
      const int col = n0 + wn + j * 16 + l15;
#pragma unroll
      for (int r = 0; r < 4; ++r) {
        const float val = flushv(acc[i][j][r], sentinel);
        if constexpr (OF)
          ((float*)O)[(long)(row0 + r) * N + col] = val;
        else
          ((u16*)O)[(long)(row0 + r) * N + col] = f2bf(val);
      }
    }
  }
}

// merged QKV projections: blocks 0..511 -> Q, 512..1023 -> K, 1024..1535 -> V^T
__global__ __launch_bounds__(256) void gemm_qkv(
    const u16* __restrict__ xb,
    const u16* __restrict__ wqb, const u16* __restrict__ wkb, const u16* __restrict__ wvb,
    u16* __restrict__ q, u16* __restrict__ k, u16* __restrict__ v)
{
  const int bid = blockIdx.x;
  const int z = bid >> 9, r = bid & 511;
  const u16 *A, *B; u16* O; int m0, n0, Nn;
  if (z < 2) {   // Q/K: [4096 tok][2048 d] = xb @ W^T
    A = xb; B = z ? wkb : wqb; O = z ? k : q;
    m0 = (r >> 4) * 128; n0 = (r & 15) * 128; Nn = 2048;
  } else {       // V^T: [2048 d][4096 tok] = Wv @ xb^T
    A = wvb; B = xb; O = v;
    m0 = (r >> 5) * 128; n0 = (r & 31) * 128; Nn = 4096;
  }
  gemm_core<false>(A, B, O, m0, n0, Nn, 7777.f);
}

// output projection: [4096][2048] fp32 = ao @ Wo^T
__global__ __launch_bounds__(256) void gemm_proj(
    const u16* __restrict__ ao, const u16* __restrict__ wob, float* __restrict__ out)
{
  const int r = blockIdx.x;   // 512
  gemm_core<true>(ao, wob, out, (r >> 4) * 128, (r & 15) * 128, 2048, 5555.f);
}

// ================= legacy GEMM (fp32-staging) — fallback path only =================
template <bool AF, bool WF, bool OF>
__global__ __launch_bounds__(256) void gemm_bt(
    const void* __restrict__ Ap,
    const void* __restrict__ Wp0, const void* __restrict__ Wp1, const void* __restrict__ Wp2,
    void* __restrict__ O0, void* __restrict__ O1, void* __restrict__ O2,
    int M, int N, int K, float sentinel)
{
  __shared__ __align__(16) u16 As[128 * 32];
  __shared__ __align__(16) u16 Bs[128 * 32];

  const void* Wp; void* O;
  if (blockIdx.z == 0)      { Wp = Wp0; O = O0; }
  else if (blockIdx.z == 1) { Wp = Wp1; O = O1; }
  else                      { Wp = Wp2; O = O2; }

  const float* Af = (const float*)Ap;  const u16* Ab = (const u16*)Ap;
  const float* Wf = (const float*)Wp;  const u16* Wb = (const u16*)Wp;

  const int tid  = threadIdx.x;
  const int wave = tid >> 6;
  const int lane = tid & 63;
  const int quad = lane >> 4;
  const int l15  = lane & 15;

  const int m0 = blockIdx.y * 128;
  const int n0 = blockIdx.x * 128;
  const int wm = (wave >> 1) * 64;
  const int wn = (wave & 1) * 64;

  const int e0 = wave * 1024 + lane * 8;
  const int e1 = e0 + 512;
  const int r0 = e0 >> 5, c0 = e0 & 31;
  const int r1 = e1 >> 5, c1 = e1 & 31;

  const long aoff0 = (long)(m0 + r0) * K + c0;
  const long aoff1 = (long)(m0 + r1) * K + c1;
  const long boff0 = (long)(n0 + r0) * K + c0;
  const long boff1 = (long)(n0 + r1) * K + c1;

  const f32x4 zero = {0.f, 0.f, 0.f, 0.f};
  f32x4 acc[4][4];
#pragma unroll
  for (int i = 0; i < 4; ++i)
#pragma unroll
    for (int j = 0; j < 4; ++j) acc[i][j] = zero;

  for (int k0 = 0; k0 < K; k0 += 32) {
    short8 a0, a1, b0, b1;
    if constexpr (AF) {
      a0 = ld8f(Af + aoff0 + k0);
      a1 = ld8f(Af + aoff1 + k0);
    } else {
      a0 = *(const short8*)(Ab + aoff0 + k0);
      a1 = *(const short8*)(Ab + aoff1 + k0);
    }
    if constexpr (WF) {
      b0 = ld8f(Wf + boff0 + k0);
      b1 = ld8f(Wf + boff1 + k0);
    } else {
      b0 = *(const short8*)(Wb + boff0 + k0);
      b1 = *(const short8*)(Wb + boff1 + k0);
    }

    __syncthreads();
    *(short8*)&As[e0] = a0;
    *(short8*)&As[e1] = a1;
    *(short8*)&Bs[e0] = b0;
    *(short8*)&Bs[e1] = b1;
    __syncthreads();

    short8 af[4], bf[4];
#pragma unroll
    for (int i = 0; i < 4; ++i)
      af[i] = *(const short8*)&As[(wm + i * 16 + l15) * 32 + quad * 8];
#pragma unroll
    for (int j = 0; j < 4; ++j)
      bf[j] = *(const short8*)&Bs[(wn + j * 16 + l15) * 32 + quad * 8];
#pragma unroll
    for (int i = 0; i < 4; ++i)
#pragma unroll
      for (int j = 0; j < 4; ++j)
        acc[i][j] = __builtin_amdgcn_mfma_f32_16x16x32_bf16(af[i], bf[j], acc[i][j], 0, 0, 0);
  }

#pragma unroll
  for (int i = 0; i < 4; ++i) {
    const int row0 = m0 + wm + i * 16 + quad * 4;
#pragma unroll
    for (int j = 0; j < 4; ++j) {
      const int col = n0 + wn + j * 16 + l15;
#pragma unroll
      for (int r = 0; r < 4; ++r) {
        const float val = flushv(acc[i][j][r], sentinel);
        if constexpr (OF)
          ((float*)O)[(long)(row0 + r) * N + col] = val;
        else
          ((u16*)O)[(long)(row0 + r) * N + col] = f2bf(val);
      }
    }
  }
}

// ================= RoPE (chunk-half), in-place on bf16 Q and K =================
__global__ __launch_bounds__(256) void rope_kernel(u16* __restrict__ Q, u16* __restrict__ K)
{
  int t = blockIdx.x * 256 + threadIdx.x;
  const int half = 2 * 2048 * 16 * 64;
  u16* P = Q;
  if (t >= half) { P = K; t -= half; }
  const int i = t & 63;
  const int s = (t >> 10) & 2047;
  const long off = ((long)(t >> 6) << 7) + i;

  const float inv_freq = __expf((float)i * -0.14391156831212787f);  // 10000^(-i/64)
  const float fr = (float)s * inv_freq;
  float sn, cs;
  __sincosf(fr, &sn, &cs);

  const float q1 = bf2f(P[off]);
  const float q2 = bf2f(P[off + 64]);
  P[off]      = f2bf(q1 * cs - q2 * sn);
  P[off + 64] = f2bf(q1 * sn + q2 * cs);
}

// ================= causal flash attention (LDS-staged, lockstep, 2-phase) =================
// R5-verified: stage K,V once per block via global_load_lds (pre-swizzled global
// source, linear LDS dest), double-buffered, 1 barrier/tile; swapped QK^T keeps
// S^T in registers; 4 blocks/CU, whole grid co-resident. AO may alias Q.
__global__ __launch_bounds__(256, 4) void attn_kernel(
    const u16* __restrict__ Q, const u16* __restrict__ K,
    const u16* __restrict__ VT, u16* __restrict__ AO)
{
  __shared__ __align__(16) u16 Kb[2][4096];  // [32 key][128 d], unit^=(row&7) swizzle
  __shared__ __align__(16) u16 Vb[2][4096];  // [128 d][32 tok], unit^=((row>>1)&3)

  const int tid  = threadIdx.x;
  const int wave = tid >> 6;
  const int lane = tid & 63;
  const int quad = lane >> 4;
  const int l15  = lane & 15;

  const int lin = blockIdx.x;                 // 0..1023
  const int xcd = lin & 7;
  const int hi  = lin >> 8;                   // 0..3
  const int g   = (lin >> 3) & 31;            // 0..31
  const int qb  = (hi & 1) ? (31 - g) : g;
  const int bh  = (xcd << 2) | hi;
  const int b   = bh >> 4;
  const int h   = bh & 15;

  const long base = (long)b * 2048 * 2048 + (long)h * 128;
  const long vtb  = (long)h * 128 * 4096 + (long)b * 2048;
  const int q0w = qb * 64 + wave * 16;
  const int qi  = q0w + l15;

  const u16* Kp0 = K + base;
  const u16* Vp0 = VT + vtb;

  auto STAGE = [&](int bs, int jb) {
#pragma unroll
    for (int gi = 0; gi < 2; ++gi) {
      const int slot = wave * 2 + gi;
      {
        const int row = slot * 4 + (lane >> 4);
        const int su  = lane & 15;
        gl16(Kp0 + (long)(jb * 32 + row) * 2048 + ((su ^ (row & 7)) << 3),
             &Kb[bs][slot * 512]);
      }
      {
        const int row = slot * 16 + (lane >> 2);
        const int su  = lane & 3;
        gl16(Vp0 + (long)row * 4096 + jb * 32 + ((su ^ ((row >> 1) & 3)) << 3),
             &Vb[bs][slot * 512]);
      }
    }
  };

  short8 qa[4];
#pragma unroll
  for (int c = 0; c < 4; ++c)
    qa[c] = *(const short8*)&Q[base + (long)(q0w + l15) * 2048 + c * 32 + quad * 8];

  const f32x4 zero = {0.f, 0.f, 0.f, 0.f};
  f32x4 o[8];
#pragma unroll
  for (int c = 0; c < 8; ++c) o[c] = zero;

  float mreg = -1e30f, lreg = 0.f;
  const float scale = 0.08838834764831845f;  // 1/sqrt(128)

  const int njb_blk = qb * 2 + 2;
  const int njb_w   = qb * 2 + 1 + (wave >> 1);

  STAGE(0, 0);
  __syncthreads();

  const int xorK = l15 & 7;
  const int xorV = (l15 >> 1) & 3;

  int cur = 0;
  for (int jb = 0; jb < njb_blk; ++jb) {
    if (jb + 1 < njb_blk) STAGE(cur ^ 1, jb + 1);

    if (jb < njb_w) {
      const int j0 = jb * 32;

      f32x4 s0T = zero, s1T = zero;
#pragma unroll
      for (int c = 0; c < 4; ++c) {
        const short8 kA = *(const short8*)&Kb[cur][l15 * 128 + (((c * 4 + quad) ^ xorK) << 3)];
        const short8 kB2 = *(const short8*)&Kb[cur][(l15 + 16) * 128 + (((c * 4 + quad) ^ xorK) << 3)];
        s0T = __builtin_amdgcn_mfma_f32_16x16x32_bf16(kA, qa[c], s0T, 0, 0, 0);
        s1T = __builtin_amdgcn_mfma_f32_16x16x32_bf16(kB2, qa[c], s1T, 0, 0, 0);
      }

      float sv0[4], sv1[4];
      float pmax = -1e30f;
      if (j0 + 31 > q0w) {
#pragma unroll
        for (int r = 0; r < 4; ++r) {
          const int k0i = j0 + quad * 4 + r;
          float s0 = s0T[r] * scale; if (k0i > qi)      s0 = -1e30f;
          float s1 = s1T[r] * scale; if (k0i + 16 > qi) s1 = -1e30f;
          sv0[r] = s0; sv1[r] = s1;
          pmax = fmaxf(pmax, fmaxf(s0, s1));
        }
      } else {
#pragma unroll
        for (int r = 0; r < 4; ++r) {
          sv0[r] = s0T[r] * scale;
          sv1[r] = s1T[r] * scale;
          pmax = fmaxf(pmax, fmaxf(sv0[r], sv1[r]));
        }
      }
      pmax = fmaxf(pmax, __shfl_xor(pmax, 16, 64));
      pmax = fmaxf(pmax, __shfl_xor(pmax, 32, 64));
      const float mprev = mreg;
      const float mnew  = fmaxf(mprev, pmax);
      const float alpha = __expf(mprev - mnew);
      float psum = 0.f;
#pragma unroll
      for (int r = 0; r < 4; ++r) {
        sv0[r] = __expf(sv0[r] - mnew);
        sv1[r] = __expf(sv1[r] - mnew);
        psum += sv0[r] + sv1[r];
      }
      psum += __shfl_xor(psum, 16, 64);
      psum += __shfl_xor(psum, 32, 64);
      lreg = lreg * alpha + psum;
      mreg = mnew;

      int w0, w1, w2, w3;
      asm("v_cvt_pk_bf16_f32 %0, %1, %2" : "=v"(w0) : "v"(sv0[0]), "v"(sv0[1]));
      asm("v_cvt_pk_bf16_f32 %0, %1, %2" : "=v"(w1) : "v"(sv0[2]), "v"(sv0[3]));
      asm("v_cvt_pk_bf16_f32 %0, %1, %2" : "=v"(w2) : "v"(sv1[0]), "v"(sv1[1]));
      asm("v_cvt_pk_bf16_f32 %0, %1, %2" : "=v"(w3) : "v"(sv1[2]), "v"(sv1[3]));
      const int srcA = l15 + ((quad & 1) << 5);
      const int srcB = srcA + 16;
      const int a0 = __shfl(w0, srcA, 64), a1 = __shfl(w1, srcA, 64);
      const int a2 = __shfl(w0, srcB, 64), a3 = __shfl(w1, srcB, 64);
      const int h0 = __shfl(w2, srcA, 64), h1 = __shfl(w3, srcA, 64);
      const int h2 = __shfl(w2, srcB, 64), h3 = __shfl(w3, srcB, 64);
      const bool hiq = quad >= 2;
      i32x4 pt;
      pt[0] = hiq ? h0 : a0;
      pt[1] = hiq ? h1 : a1;
      pt[2] = hiq ? h2 : a2;
      pt[3] = hiq ? h3 : a3;
      const short8 pa = *(const short8*)&pt;

      float av[4];
#pragma unroll
      for (int r = 0; r < 4; ++r) av[r] = __shfl(alpha, quad * 4 + r, 64);
#pragma unroll
      for (int c = 0; c < 8; ++c) {
        o[c][0] *= av[0]; o[c][1] *= av[1]; o[c][2] *= av[2]; o[c][3] *= av[3];
      }

#pragma unroll
      for (int c = 0; c < 8; ++c) {
        const short8 vf = *(const short8*)&Vb[cur][(c * 16 + l15) * 32 + ((quad ^ xorV) << 3)];
        o[c] = __builtin_amdgcn_mfma_f32_16x16x32_bf16(pa, vf, o[c], 0, 0, 0);
      }
    }

    __syncthreads();
    cur ^= 1;
  }

#pragma unroll
  for (int r = 0; r < 4; ++r) {
    const float lr  = __shfl(lreg, quad * 4 + r, 64);
    const float inv = 1.0f / lr;
    const long rowoff = base + (long)(q0w + quad * 4 + r) * 2048;
#pragma unroll
    for (int c = 0; c < 8; ++c)
      AO[rowoff + c * 16 + l15] = f2bf(flushv(o[c][r] * inv, 9999.f));
  }
}

// ================= diagnostic fill =================
__global__ __launch_bounds__(256) void fill_kernel(float* __restrict__ out, long n, float v)
{
  const long t = (long)blockIdx.x * 256 + threadIdx.x;
  if (t < n) out[t] = v;
}

// ================= launch =================
extern "C" void kernel_launch(void* const* d_in, const int* in_sizes, int n_in,
                              void* d_out, int out_size, void* d_ws, size_t ws_size,
                              hipStream_t stream)
{
  // Inputs fp32 (x, Wq, Wk, Wv, Wo); OUTPUT fp32 (reference dtype).
  const float* x  = (const float*)d_in[0];
  const float* Wq = (const float*)d_in[1];
  const float* Wk = (const float*)d_in[2];
  const float* Wv = (const float*)d_in[3];
  const float* Wo = (const float*)d_in[4];
  float* out = (float*)d_out;

  const long QSZ = (long)2 * 2048 * 2048;  // 8388608 elems
  const long WSZ = QSZ / 2;                // 2048*2048 weight elems

  u16* ws = (u16*)d_ws;
  u16* q  = ws;            // bf16 internal
  u16* k  = ws + QSZ;
  u16* v  = ws + 2 * QSZ;  // V^T: [2048 d][4096 tok]
  u16* ao = q;             // attention output in-place over q (partition-safe)

  if (ws_size >= (size_t)6 * QSZ * sizeof(u16)) {
    // ---- fast path: pre-convert to bf16 + prefetch-dbuf global_load_lds GEMMs ----
    u16* xb  = ws + 3 * QSZ;        // x as bf16 [4096][2048]
    u16* wqb = ws + 4 * QSZ;
    u16* wkb = wqb + WSZ;
    u16* wvb = wqb + 2 * WSZ;
    u16* wob = wqb + 3 * WSZ;

    cvt_all<<<12288, 256, 0, stream>>>(x, Wq, Wk, Wv, Wo, xb, wqb, wkb, wvb, wob);
    // merged Q,K projections + V^T (one launch, 1536 blocks)
    gemm_qkv<<<1536, 256, 0, stream>>>(xb, wqb, wkb, wvb, q, k, v);
    rope_kernel<<<32768, 256, 0, stream>>>(q, k);
    attn_kernel<<<1024, 256, 0, stream>>>(q, k, v, ao);
    gemm_proj<<<512, 256, 0, stream>>>(ao, wob, out);
    return;
  }

  // ---- fallback: R5 path (fp32-staging GEMMs), needs 48 MB ----
  if (ws_size < (size_t)3 * QSZ * sizeof(u16)) {
    fill_kernel<<<(int)((QSZ + 255) / 256), 256, 0, stream>>>(out, QSZ, 1111.f);
    return;
  }

  gemm_bt<true, true, false><<<dim3(16, 32, 2), 256, 0, stream>>>(
      x, Wq, Wk, Wk, q, k, k, 4096, 2048, 2048, 7777.f);
  gemm_bt<true, true, false><<<dim3(32, 16, 1), 256, 0, stream>>>(
      Wv, x, x, x, v, v, v, 2048, 4096, 2048, 7777.f);
  rope_kernel<<<32768, 256, 0, stream>>>(q, k);
  attn_kernel<<<1024, 256, 0, stream>>>(q, k, v, ao);
  gemm_bt<false, true, true><<<dim3(16, 32, 1), 256, 0, stream>>>(
      ao, Wo, Wo, Wo, out, out, out, 4096, 2048, 2048, 5555.f);
}

// Round 8
// 393.041 us; speedup vs baseline: 1.8176x; 1.0740x over previous
//
#include <hip/hip_runtime.h>

typedef unsigned short u16;
typedef __attribute__((ext_vector_type(8))) short short8;
typedef __attribute__((ext_vector_type(4))) float f32x4;
typedef __attribute__((ext_vector_type(4))) int i32x4;

// ---------- bf16 helpers (RNE) ----------
__device__ __forceinline__ float bf2f(u16 u) {
  union { unsigned u; float f; } v; v.u = ((unsigned)u) << 16; return v.f;
}
__device__ __forceinline__ u16 f2bf(float f) {
  union { float f; unsigned u; } v; v.f = f;
  unsigned r = (v.u + 0x7FFFu + ((v.u >> 16) & 1u)) >> 16;
  return (u16)r;
}
__device__ __forceinline__ float flushv(float t, float sentinel) {
  if (t != t || fabsf(t) > 3.0e38f) return sentinel;
  return t;
}
// load 8 fp32 and convert to bf16x8
__device__ __forceinline__ short8 ld8f(const float* p) {
  const float4 f0 = *(const float4*)p;
  const float4 f1 = *(const float4*)(p + 4);
  short8 r;
  r[0] = (short)f2bf(f0.x); r[1] = (short)f2bf(f0.y);
  r[2] = (short)f2bf(f0.z); r[3] = (short)f2bf(f0.w);
  r[4] = (short)f2bf(f1.x); r[5] = (short)f2bf(f1.y);
  r[6] = (short)f2bf(f1.z); r[7] = (short)f2bf(f1.w);
  return r;
}

// async global->LDS, 16B per lane; LDS dest = wave-uniform base + lane*16 (linear)
__device__ __forceinline__ void gl16(const u16* g, u16* l) {
  __builtin_amdgcn_global_load_lds(
      (const __attribute__((address_space(1))) void*)g,
      (__attribute__((address_space(3))) void*)l, 16, 0, 0);
}

// counted vmcnt wait (asm: compiler cannot fold it into a full drain) + IR fence
#define VWAIT(N) asm volatile("s_waitcnt vmcnt(" #N ")" ::: "memory")
// raw barrier without vmcnt drain; sched_barrier pins machine scheduler (rule #18)
#define SBAR() do { __builtin_amdgcn_sched_barrier(0); \
                    __builtin_amdgcn_s_barrier(); \
                    __builtin_amdgcn_sched_barrier(0); } while (0)

// ================= fp32 -> bf16 conversion (single pass, 5 tensors) =================
// blocks 0..8191: the four 2048x2048 weights (2048 blocks each)
// blocks 8192..12287: x (4096 blocks)
__global__ __launch_bounds__(256) void cvt_all(
    const float* __restrict__ x,
    const float* __restrict__ Wq, const float* __restrict__ Wk,
    const float* __restrict__ Wv, const float* __restrict__ Wo,
    u16* __restrict__ xb, u16* __restrict__ wqb, u16* __restrict__ wkb,
    u16* __restrict__ wvb, u16* __restrict__ wob)
{
  const int bid = blockIdx.x;
  const float* s; u16* d; long t;
  if (bid < 8192) {
    const int which = bid >> 11;
    t = (long)(bid & 2047) * 256 + threadIdx.x;
    if (which == 0)      { s = Wq; d = wqb; }
    else if (which == 1) { s = Wk; d = wkb; }
    else if (which == 2) { s = Wv; d = wvb; }
    else                 { s = Wo; d = wob; }
  } else {
    s = x; d = xb;
    t = (long)(bid - 8192) * 256 + threadIdx.x;
  }
  *(short8*)&d[t * 8] = ld8f(s + t * 8);
}

// ================= GEMM core: C[M,N] = A[M,K] @ B[N,K]^T, bf16 in, K=2048 =================
// 128x128 tile, BK=32, double-buffered LDS via global_load_lds.
// NEW vs R7: (1) conflict-free LDS: unit ^= (row>>1)&3 swizzle applied on the
// pre-swizzled GLOBAL source (stage) and on the ds_read address (both-sides, rule #21).
// Derivation: 16B-group = 4*(row&1) | (quad ^ ((row>>1)&3)) -> 8 groups x 2 lanes = free.
// (2) counted vmcnt: stage(next) issued, then VWAIT(4) waits only the OLDER 4 loads
// (current buffer) + raw s_barrier (no vmcnt(0) drain) -> the fresh stage spans two
// compute phases. Cross-wave: every wave passes VWAIT(4) before the barrier, so the
// tile is collectively complete after it. Trailing SBAR handles WAR.
template <bool OF>
__device__ __forceinline__ void gemm_core(
    const u16* __restrict__ Ap, const u16* __restrict__ Bp,
    void* __restrict__ O, int m0, int n0, int N, float sentinel)
{
  __shared__ __align__(16) u16 As[2][128 * 32];
  __shared__ __align__(16) u16 Bs[2][128 * 32];
  constexpr int K = 2048;

  const int tid  = threadIdx.x;
  const int wave = tid >> 6;
  const int lane = tid & 63;
  const int quad = lane >> 4;
  const int l15  = lane & 15;

  const int wm = (wave >> 1) * 64;
  const int wn = (wave & 1) * 64;

  // staging geometry: slot = wave*2+gi covers 16 rows; lane>>2 = row-in-slot,
  // lane&3 = 16B unit. Source col pre-swizzled: unit ^= (row>>1)&3.
  // Note (row+16)>>1 & 3 == (row>>1)&3, so both slots share one swizzled col.
  const int srow = lane >> 2;
  const int su   = lane & 3;
  const int r0   = wave * 32 + srow;       // slot0 row, slot1 = r0+16
  const int csw  = ((su ^ ((r0 >> 1) & 3)) << 3);
  const u16* Ag0 = Ap + (long)(m0 + r0) * K + csw;
  const u16* Ag1 = Ag0 + 16 * (long)K;
  const u16* Bg0 = Bp + (long)(n0 + r0) * K + csw;
  const u16* Bg1 = Bg0 + 16 * (long)K;
  const int sl0 = (wave * 2 + 0) * 512;
  const int sl1 = (wave * 2 + 1) * 512;

  // ds_read swizzle: (row>>1)&3 == (l15>>1)&3 here (wm, wn, i*16 all = 0 mod 8)
  const int xsw = ((l15 >> 1) & 3) << 3;

  const f32x4 zero = {0.f, 0.f, 0.f, 0.f};
  f32x4 acc[4][4];
#pragma unroll
  for (int i = 0; i < 4; ++i)
#pragma unroll
    for (int j = 0; j < 4; ++j) acc[i][j] = zero;

  auto STAGE = [&](int bs, int k0) {
    gl16(Ag0 + k0, &As[bs][sl0]); gl16(Ag1 + k0, &As[bs][sl1]);
    gl16(Bg0 + k0, &Bs[bs][sl0]); gl16(Bg1 + k0, &Bs[bs][sl1]);
  };
  auto COMPUTE = [&](const u16* Ab, const u16* Bb) {
    short8 af[4], bf[4];
#pragma unroll
    for (int i = 0; i < 4; ++i)
      af[i] = *(const short8*)&Ab[(wm + i * 16 + l15) * 32 + ((quad << 3) ^ xsw)];
#pragma unroll
    for (int j = 0; j < 4; ++j)
      bf[j] = *(const short8*)&Bb[(wn + j * 16 + l15) * 32 + ((quad << 3) ^ xsw)];
#pragma unroll
    for (int i = 0; i < 4; ++i)
#pragma unroll
      for (int j = 0; j < 4; ++j)
        acc[i][j] = __builtin_amdgcn_mfma_f32_16x16x32_bf16(af[i], bf[j], acc[i][j], 0, 0, 0);
  };

  STAGE(0, 0);                       // prologue: 4 loads in flight

#pragma unroll 1
  for (int k0 = 0; k0 < K; k0 += 64) {
    // step A: prefetch buf1 @ k0+32 (always in range), compute buf0 @ k0
    STAGE(1, k0 + 32);               // outstanding: 4 old (buf0) + 4 new
    VWAIT(4); SBAR();                // buf0 collectively resident
    COMPUTE(As[0], Bs[0]);
    SBAR();                          // WAR: all waves done reading buf0

    // step B: prefetch buf0 @ k0+64 (guarded), compute buf1 @ k0+32
    if (k0 + 64 < K) { STAGE(0, k0 + 64); VWAIT(4); }
    else             { VWAIT(0); }
    SBAR();
    COMPUTE(As[1], Bs[1]);
    SBAR();
  }

  // C/D layout: col = lane&15, row = quad*4 + reg (verified m89/m91)
#pragma unroll
  for (int i = 0; i < 4; ++i) {
    const int row0 = m0 + wm + i * 16 + quad * 4;
#pragma unroll
    for (int j = 0; j < 4; ++j) {
      const int col = n0 + wn + j * 16 + l15;
#pragma unroll
      for (int r = 0; r < 4; ++r) {
        const float val = flushv(acc[i][j][r], sentinel);
        if constexpr (OF)
          ((float*)O)[(long)(row0 + r) * N + col] = val;
        else
          ((u16*)O)[(long)(row0 + r) * N + col] = f2bf(val);
      }
    }
  }
}

// merged QKV projections: blocks 0..511 -> Q, 512..1023 -> K, 1024..1535 -> V^T
__global__ __launch_bounds__(256) void gemm_qkv(
    const u16* __restrict__ xb,
    const u16* __restrict__ wqb, const u16* __restrict__ wkb, const u16* __restrict__ wvb,
    u16* __restrict__ q, u16* __restrict__ k, u16* __restrict__ v)
{
  const int bid = blockIdx.x;
  const int z = bid >> 9, r = bid & 511;
  const u16 *A, *B; u16* O; int m0, n0, Nn;
  if (z < 2) {   // Q/K: [4096 tok][2048 d] = xb @ W^T
    A = xb; B = z ? wkb : wqb; O = z ? k : q;
    m0 = (r >> 4) * 128; n0 = (r & 15) * 128; Nn = 2048;
  } else {       // V^T: [2048 d][4096 tok] = Wv @ xb^T
    A = wvb; B = xb; O = v;
    m0 = (r >> 5) * 128; n0 = (r & 31) * 128; Nn = 4096;
  }
  gemm_core<false>(A, B, O, m0, n0, Nn, 7777.f);
}

// output projection: [4096][2048] fp32 = ao @ Wo^T
__global__ __launch_bounds__(256) void gemm_proj(
    const u16* __restrict__ ao, const u16* __restrict__ wob, float* __restrict__ out)
{
  const int r = blockIdx.x;   // 512
  gemm_core<true>(ao, wob, out, (r >> 4) * 128, (r & 15) * 128, 2048, 5555.f);
}

// ================= legacy GEMM (fp32-staging) — fallback path only =================
template <bool AF, bool WF, bool OF>
__global__ __launch_bounds__(256) void gemm_bt(
    const void* __restrict__ Ap,
    const void* __restrict__ Wp0, const void* __restrict__ Wp1, const void* __restrict__ Wp2,
    void* __restrict__ O0, void* __restrict__ O1, void* __restrict__ O2,
    int M, int N, int K, float sentinel)
{
  __shared__ __align__(16) u16 As[128 * 32];
  __shared__ __align__(16) u16 Bs[128 * 32];

  const void* Wp; void* O;
  if (blockIdx.z == 0)      { Wp = Wp0; O = O0; }
  else if (blockIdx.z == 1) { Wp = Wp1; O = O1; }
  else                      { Wp = Wp2; O = O2; }

  const float* Af = (const float*)Ap;  const u16* Ab = (const u16*)Ap;
  const float* Wf = (const float*)Wp;  const u16* Wb = (const u16*)Wp;

  const int tid  = threadIdx.x;
  const int wave = tid >> 6;
  const int lane = tid & 63;
  const int quad = lane >> 4;
  const int l15  = lane & 15;

  const int m0 = blockIdx.y * 128;
  const int n0 = blockIdx.x * 128;
  const int wm = (wave >> 1) * 64;
  const int wn = (wave & 1) * 64;

  const int e0 = wave * 1024 + lane * 8;
  const int e1 = e0 + 512;
  const int r0 = e0 >> 5, c0 = e0 & 31;
  const int r1 = e1 >> 5, c1 = e1 & 31;

  const long aoff0 = (long)(m0 + r0) * K + c0;
  const long aoff1 = (long)(m0 + r1) * K + c1;
  const long boff0 = (long)(n0 + r0) * K + c0;
  const long boff1 = (long)(n0 + r1) * K + c1;

  const f32x4 zero = {0.f, 0.f, 0.f, 0.f};
  f32x4 acc[4][4];
#pragma unroll
  for (int i = 0; i < 4; ++i)
#pragma unroll
    for (int j = 0; j < 4; ++j) acc[i][j] = zero;

  for (int k0 = 0; k0 < K; k0 += 32) {
    short8 a0, a1, b0, b1;
    if constexpr (AF) {
      a0 = ld8f(Af + aoff0 + k0);
      a1 = ld8f(Af + aoff1 + k0);
    } else {
      a0 = *(const short8*)(Ab + aoff0 + k0);
      a1 = *(const short8*)(Ab + aoff1 + k0);
    }
    if constexpr (WF) {
      b0 = ld8f(Wf + boff0 + k0);
      b1 = ld8f(Wf + boff1 + k0);
    } else {
      b0 = *(const short8*)(Wb + boff0 + k0);
      b1 = *(const short8*)(Wb + boff1 + k0);
    }

    __syncthreads();
    *(short8*)&As[e0] = a0;
    *(short8*)&As[e1] = a1;
    *(short8*)&Bs[e0] = b0;
    *(short8*)&Bs[e1] = b1;
    __syncthreads();

    short8 af[4], bf[4];
#pragma unroll
    for (int i = 0; i < 4; ++i)
      af[i] = *(const short8*)&As[(wm + i * 16 + l15) * 32 + quad * 8];
#pragma unroll
    for (int j = 0; j < 4; ++j)
      bf[j] = *(const short8*)&Bs[(wn + j * 16 + l15) * 32 + quad * 8];
#pragma unroll
    for (int i = 0; i < 4; ++i)
#pragma unroll
      for (int j = 0; j < 4; ++j)
        acc[i][j] = __builtin_amdgcn_mfma_f32_16x16x32_bf16(af[i], bf[j], acc[i][j], 0, 0, 0);
  }

#pragma unroll
  for (int i = 0; i < 4; ++i) {
    const int row0 = m0 + wm + i * 16 + quad * 4;
#pragma unroll
    for (int j = 0; j < 4; ++j) {
      const int col = n0 + wn + j * 16 + l15;
#pragma unroll
      for (int r = 0; r < 4; ++r) {
        const float val = flushv(acc[i][j][r], sentinel);
        if constexpr (OF)
          ((float*)O)[(long)(row0 + r) * N + col] = val;
        else
          ((u16*)O)[(long)(row0 + r) * N + col] = f2bf(val);
      }
    }
  }
}

// ================= RoPE (chunk-half), in-place, vectorized x8 (G13) =================
// thread handles 8 consecutive i of one (tensor,row): short8 load/store of both
// halves; inv_freq chain = 1 __expf + 7 mults by 10000^(-1/64).
__global__ __launch_bounds__(256) void rope_kernel(u16* __restrict__ Q, u16* __restrict__ K)
{
  int t = blockIdx.x * 256 + threadIdx.x;
  const int per = 524288;              // 65536 rows * 8 i-groups
  u16* P = Q;
  if (t >= per) { P = K; t -= per; }
  const int i8  = t & 7;
  const int row = t >> 3;              // (b*2048 + s)*16 + h
  const int s   = (row >> 4) & 2047;
  const long off = (long)row * 128 + i8 * 8;

  short8 va = *(const short8*)&P[off];
  short8 vb = *(const short8*)&P[off + 64];

  const float fs = (float)s;
  float invf = __expf((float)(i8 * 8) * -0.14391156831212787f);  // 10000^(-i/64)
  const float step = 0.86596432336f;                             // 10000^(-1/64)
#pragma unroll
  for (int j = 0; j < 8; ++j) {
    float sn, cs;
    __sincosf(fs * invf, &sn, &cs);
    const float q1 = bf2f((u16)va[j]);
    const float q2 = bf2f((u16)vb[j]);
    va[j] = (short)f2bf(q1 * cs - q2 * sn);
    vb[j] = (short)f2bf(q1 * sn + q2 * cs);
    invf *= step;
  }
  *(short8*)&P[off]      = va;
  *(short8*)&P[off + 64] = vb;
}

// ================= causal flash attention (LDS-staged, lockstep, 2-phase) =================
// R5-verified: stage K,V once per block via global_load_lds (pre-swizzled global
// source, linear LDS dest), double-buffered, 1 barrier/tile; swapped QK^T keeps
// S^T in registers; 4 blocks/CU, whole grid co-resident. AO may alias Q.
__global__ __launch_bounds__(256, 4) void attn_kernel(
    const u16* __restrict__ Q, const u16* __restrict__ K,
    const u16* __restrict__ VT, u16* __restrict__ AO)
{
  __shared__ __align__(16) u16 Kb[2][4096];  // [32 key][128 d], unit^=(row&7) swizzle
  __shared__ __align__(16) u16 Vb[2][4096];  // [128 d][32 tok], unit^=((row>>1)&3)

  const int tid  = threadIdx.x;
  const int wave = tid >> 6;
  const int lane = tid & 63;
  const int quad = lane >> 4;
  const int l15  = lane & 15;

  const int lin = blockIdx.x;                 // 0..1023
  const int xcd = lin & 7;
  const int hi  = lin >> 8;                   // 0..3
  const int g   = (lin >> 3) & 31;            // 0..31
  const int qb  = (hi & 1) ? (31 - g) : g;
  const int bh  = (xcd << 2) | hi;
  const int b   = bh >> 4;
  const int h   = bh & 15;

  const long base = (long)b * 2048 * 2048 + (long)h * 128;
  const long vtb  = (long)h * 128 * 4096 + (long)b * 2048;
  const int q0w = qb * 64 + wave * 16;
  const int qi  = q0w + l15;

  const u16* Kp0 = K + base;
  const u16* Vp0 = VT + vtb;

  auto STAGE = [&](int bs, int jb) {
#pragma unroll
    for (int gi = 0; gi < 2; ++gi) {
      const int slot = wave * 2 + gi;
      {
        const int row = slot * 4 + (lane >> 4);
        const int su  = lane & 15;
        gl16(Kp0 + (long)(jb * 32 + row) * 2048 + ((su ^ (row & 7)) << 3),
             &Kb[bs][slot * 512]);
      }
      {
        const int row = slot * 16 + (lane >> 2);
        const int su  = lane & 3;
        gl16(Vp0 + (long)row * 4096 + jb * 32 + ((su ^ ((row >> 1) & 3)) << 3),
             &Vb[bs][slot * 512]);
      }
    }
  };

  short8 qa[4];
#pragma unroll
  for (int c = 0; c < 4; ++c)
    qa[c] = *(const short8*)&Q[base + (long)(q0w + l15) * 2048 + c * 32 + quad * 8];

  const f32x4 zero = {0.f, 0.f, 0.f, 0.f};
  f32x4 o[8];
#pragma unroll
  for (int c = 0; c < 8; ++c) o[c] = zero;

  float mreg = -1e30f, lreg = 0.f;
  const float scale = 0.08838834764831845f;  // 1/sqrt(128)

  const int njb_blk = qb * 2 + 2;
  const int njb_w   = qb * 2 + 1 + (wave >> 1);

  STAGE(0, 0);
  __syncthreads();

  const int xorK = l15 & 7;
  const int xorV = (l15 >> 1) & 3;

  int cur = 0;
  for (int jb = 0; jb < njb_blk; ++jb) {
    if (jb + 1 < njb_blk) STAGE(cur ^ 1, jb + 1);

    if (jb < njb_w) {
      const int j0 = jb * 32;

      f32x4 s0T = zero, s1T = zero;
#pragma unroll
      for (int c = 0; c < 4; ++c) {
        const short8 kA = *(const short8*)&Kb[cur][l15 * 128 + (((c * 4 + quad) ^ xorK) << 3)];
        const short8 kB2 = *(const short8*)&Kb[cur][(l15 + 16) * 128 + (((c * 4 + quad) ^ xorK) << 3)];
        s0T = __builtin_amdgcn_mfma_f32_16x16x32_bf16(kA, qa[c], s0T, 0, 0, 0);
        s1T = __builtin_amdgcn_mfma_f32_16x16x32_bf16(kB2, qa[c], s1T, 0, 0, 0);
      }

      float sv0[4], sv1[4];
      float pmax = -1e30f;
      if (j0 + 31 > q0w) {
#pragma unroll
        for (int r = 0; r < 4; ++r) {
          const int k0i = j0 + quad * 4 + r;
          float s0 = s0T[r] * scale; if (k0i > qi)      s0 = -1e30f;
          float s1 = s1T[r] * scale; if (k0i + 16 > qi) s1 = -1e30f;
          sv0[r] = s0; sv1[r] = s1;
          pmax = fmaxf(pmax, fmaxf(s0, s1));
        }
      } else {
#pragma unroll
        for (int r = 0; r < 4; ++r) {
          sv0[r] = s0T[r] * scale;
          sv1[r] = s1T[r] * scale;
          pmax = fmaxf(pmax, fmaxf(sv0[r], sv1[r]));
        }
      }
      pmax = fmaxf(pmax, __shfl_xor(pmax, 16, 64));
      pmax = fmaxf(pmax, __shfl_xor(pmax, 32, 64));
      const float mprev = mreg;
      const float mnew  = fmaxf(mprev, pmax);
      const float alpha = __expf(mprev - mnew);
      float psum = 0.f;
#pragma unroll
      for (int r = 0; r < 4; ++r) {
        sv0[r] = __expf(sv0[r] - mnew);
        sv1[r] = __expf(sv1[r] - mnew);
        psum += sv0[r] + sv1[r];
      }
      psum += __shfl_xor(psum, 16, 64);
      psum += __shfl_xor(psum, 32, 64);
      lreg = lreg * alpha + psum;
      mreg = mnew;

      int w0, w1, w2, w3;
      asm("v_cvt_pk_bf16_f32 %0, %1, %2" : "=v"(w0) : "v"(sv0[0]), "v"(sv0[1]));
      asm("v_cvt_pk_bf16_f32 %0, %1, %2" : "=v"(w1) : "v"(sv0[2]), "v"(sv0[3]));
      asm("v_cvt_pk_bf16_f32 %0, %1, %2" : "=v"(w2) : "v"(sv1[0]), "v"(sv1[1]));
      asm("v_cvt_pk_bf16_f32 %0, %1, %2" : "=v"(w3) : "v"(sv1[2]), "v"(sv1[3]));
      const int srcA = l15 + ((quad & 1) << 5);
      const int srcB = srcA + 16;
      const int a0 = __shfl(w0, srcA, 64), a1 = __shfl(w1, srcA, 64);
      const int a2 = __shfl(w0, srcB, 64), a3 = __shfl(w1, srcB, 64);
      const int h0 = __shfl(w2, srcA, 64), h1 = __shfl(w3, srcA, 64);
      const int h2 = __shfl(w2, srcB, 64), h3 = __shfl(w3, srcB, 64);
      const bool hiq = quad >= 2;
      i32x4 pt;
      pt[0] = hiq ? h0 : a0;
      pt[1] = hiq ? h1 : a1;
      pt[2] = hiq ? h2 : a2;
      pt[3] = hiq ? h3 : a3;
      const short8 pa = *(const short8*)&pt;

      float av[4];
#pragma unroll
      for (int r = 0; r < 4; ++r) av[r] = __shfl(alpha, quad * 4 + r, 64);
#pragma unroll
      for (int c = 0; c < 8; ++c) {
        o[c][0] *= av[0]; o[c][1] *= av[1]; o[c][2] *= av[2]; o[c][3] *= av[3];
      }

#pragma unroll
      for (int c = 0; c < 8; ++c) {
        const short8 vf = *(const short8*)&Vb[cur][(c * 16 + l15) * 32 + ((quad ^ xorV) << 3)];
        o[c] = __builtin_amdgcn_mfma_f32_16x16x32_bf16(pa, vf, o[c], 0, 0, 0);
      }
    }

    __syncthreads();
    cur ^= 1;
  }

#pragma unroll
  for (int r = 0; r < 4; ++r) {
    const float lr  = __shfl(lreg, quad * 4 + r, 64);
    const float inv = 1.0f / lr;
    const long rowoff = base + (long)(q0w + quad * 4 + r) * 2048;
#pragma unroll
    for (int c = 0; c < 8; ++c)
      AO[rowoff + c * 16 + l15] = f2bf(flushv(o[c][r] * inv, 9999.f));
  }
}

// ================= diagnostic fill =================
__global__ __launch_bounds__(256) void fill_kernel(float* __restrict__ out, long n, float v)
{
  const long t = (long)blockIdx.x * 256 + threadIdx.x;
  if (t < n) out[t] = v;
}

// ================= launch =================
extern "C" void kernel_launch(void* const* d_in, const int* in_sizes, int n_in,
                              void* d_out, int out_size, void* d_ws, size_t ws_size,
                              hipStream_t stream)
{
  // Inputs fp32 (x, Wq, Wk, Wv, Wo); OUTPUT fp32 (reference dtype).
  const float* x  = (const float*)d_in[0];
  const float* Wq = (const float*)d_in[1];
  const float* Wk = (const float*)d_in[2];
  const float* Wv = (const float*)d_in[3];
  const float* Wo = (const float*)d_in[4];
  float* out = (float*)d_out;

  const long QSZ = (long)2 * 2048 * 2048;  // 8388608 elems
  const long WSZ = QSZ / 2;                // 2048*2048 weight elems

  u16* ws = (u16*)d_ws;
  u16* q  = ws;            // bf16 internal
  u16* k  = ws + QSZ;
  u16* v  = ws + 2 * QSZ;  // V^T: [2048 d][4096 tok]
  u16* ao = q;             // attention output in-place over q (partition-safe)

  if (ws_size >= (size_t)6 * QSZ * sizeof(u16)) {
    // ---- fast path: bf16 pre-convert + swizzled counted-vmcnt GEMMs ----
    u16* xb  = ws + 3 * QSZ;        // x as bf16 [4096][2048]
    u16* wqb = ws + 4 * QSZ;
    u16* wkb = wqb + WSZ;
    u16* wvb = wqb + 2 * WSZ;
    u16* wob = wqb + 3 * WSZ;

    cvt_all<<<12288, 256, 0, stream>>>(x, Wq, Wk, Wv, Wo, xb, wqb, wkb, wvb, wob);
    gemm_qkv<<<1536, 256, 0, stream>>>(xb, wqb, wkb, wvb, q, k, v);
    rope_kernel<<<4096, 256, 0, stream>>>(q, k);
    attn_kernel<<<1024, 256, 0, stream>>>(q, k, v, ao);
    gemm_proj<<<512, 256, 0, stream>>>(ao, wob, out);
    return;
  }

  // ---- fallback: R5 path (fp32-staging GEMMs), needs 48 MB ----
  if (ws_size < (size_t)3 * QSZ * sizeof(u16)) {
    fill_kernel<<<(int)((QSZ + 255) / 256), 256, 0, stream>>>(out, QSZ, 1111.f);
    return;
  }

  gemm_bt<true, true, false><<<dim3(16, 32, 2), 256, 0, stream>>>(
      x, Wq, Wk, Wk, q, k, k, 4096, 2048, 2048, 7777.f);
  gemm_bt<true, true, false><<<dim3(32, 16, 1), 256, 0, stream>>>(
      Wv, x, x, x, v, v, v, 2048, 4096, 2048, 7777.f);
  rope_kernel<<<4096, 256, 0, stream>>>(q, k);
  attn_kernel<<<1024, 256, 0, stream>>>(q, k, v, ao);
  gemm_bt<false, true, true><<<dim3(16, 32, 1), 256, 0, stream>>>(
      ao, Wo, Wo, Wo, out, out, out, 4096, 2048, 2048, 5555.f);
}

// Round 9
// 389.847 us; speedup vs baseline: 1.8325x; 1.0082x over previous
//
#include <hip/hip_runtime.h>

typedef unsigned short u16;
typedef __attribute__((ext_vector_type(8))) short short8;
typedef __attribute__((ext_vector_type(4))) float f32x4;
typedef __attribute__((ext_vector_type(4))) int i32x4;

// ---------- bf16 helpers (RNE) ----------
__device__ __forceinline__ float bf2f(u16 u) {
  union { unsigned u; float f; } v; v.u = ((unsigned)u) << 16; return v.f;
}
__device__ __forceinline__ u16 f2bf(float f) {
  union { float f; unsigned u; } v; v.f = f;
  unsigned r = (v.u + 0x7FFFu + ((v.u >> 16) & 1u)) >> 16;
  return (u16)r;
}
__device__ __forceinline__ float flushv(float t, float sentinel) {
  if (t != t || fabsf(t) > 3.0e38f) return sentinel;
  return t;
}
// load 8 fp32 and convert to bf16x8
__device__ __forceinline__ short8 ld8f(const float* p) {
  const float4 f0 = *(const float4*)p;
  const float4 f1 = *(const float4*)(p + 4);
  short8 r;
  r[0] = (short)f2bf(f0.x); r[1] = (short)f2bf(f0.y);
  r[2] = (short)f2bf(f0.z); r[3] = (short)f2bf(f0.w);
  r[4] = (short)f2bf(f1.x); r[5] = (short)f2bf(f1.y);
  r[6] = (short)f2bf(f1.z); r[7] = (short)f2bf(f1.w);
  return r;
}

// async global->LDS, 16B per lane; LDS dest = wave-uniform base + lane*16 (linear)
__device__ __forceinline__ void gl16(const u16* g, u16* l) {
  __builtin_amdgcn_global_load_lds(
      (const __attribute__((address_space(1))) void*)g,
      (__attribute__((address_space(3))) void*)l, 16, 0, 0);
}

// counted vmcnt wait (asm: compiler cannot fold it into a full drain) + IR fence
#define VWAIT(N) do { \
  asm volatile("s_waitcnt vmcnt(" #N ")" ::: "memory"); \
  __builtin_amdgcn_sched_barrier(0); } while (0)
// raw barrier WITHOUT vmcnt drain (T4: loads stay in flight across it)
#define SBAR() do { __builtin_amdgcn_sched_barrier(0); \
                    __builtin_amdgcn_s_barrier(); \
                    __builtin_amdgcn_sched_barrier(0); } while (0)

// ================= fp32 -> bf16 conversion (single pass, 5 tensors) =================
__global__ __launch_bounds__(256) void cvt_all(
    const float* __restrict__ x,
    const float* __restrict__ Wq, const float* __restrict__ Wk,
    const float* __restrict__ Wv, const float* __restrict__ Wo,
    u16* __restrict__ xb, u16* __restrict__ wqb, u16* __restrict__ wkb,
    u16* __restrict__ wvb, u16* __restrict__ wob)
{
  const int bid = blockIdx.x;
  const float* s; u16* d; long t;
  if (bid < 8192) {
    const int which = bid >> 11;
    t = (long)(bid & 2047) * 256 + threadIdx.x;
    if (which == 0)      { s = Wq; d = wqb; }
    else if (which == 1) { s = Wk; d = wkb; }
    else if (which == 2) { s = Wv; d = wvb; }
    else                 { s = Wo; d = wob; }
  } else {
    s = x; d = xb;
    t = (long)(bid - 8192) * 256 + threadIdx.x;
  }
  *(short8*)&d[t * 8] = ld8f(s + t * 8);
}

// ================= 8-phase 256^2 GEMM: [Q|K] = xb @ [Wq;Wk]^T =================
// M=4096 (tok), N=4096 (stacked Q|K outputs), K=2048. Grid 256 = 1 block/CU (no tail).
// 512 thr (8 waves, 2Mx4N; wave tile 128x64, acc[8][4]). LDS 128KB: 2 dbuf x (A 32K + B 32K).
// Per iteration (1 K-tile of BK=64, 4 phases x 16 MFMA):
//   ph0: ds bf[4][2]+af(0,1) | stage-A(next -> buf^1) | MFMA(m0,m1) | s_barrier
//   ph1: ds af(2,3)          | stage-B(next)          | MFMA        | s_barrier
//   ph2: ds af(4,5)          |                        | MFMA        | s_barrier
//   ph3: ds af(6,7)          |                        | MFMA | VWAIT(0) | s_barrier
// Raw s_barrier does NOT drain vmcnt (T4) -> stages get 2-4 phases of cover.
// Staging writes buf^1 only (no WAR with computed buf); setprio(1) around MFMA (T5).
// Swizzle (T2, rule #21 both-sides): stage src unit = lu^lrow; read unit = (ks*4+quad)^(l15&7).
__global__ __launch_bounds__(512, 2) void gemm_qk8(
    const u16* __restrict__ Ap, const u16* __restrict__ wqb, const u16* __restrict__ wkb,
    u16* __restrict__ q, u16* __restrict__ k)
{
  __shared__ __align__(16) u16 As[2][256 * 64];
  __shared__ __align__(16) u16 Bs[2][256 * 64];
  constexpr int K = 2048;

  const int tid  = threadIdx.x;
  const int wave = tid >> 6;           // 0..7
  const int lane = tid & 63;
  const int quad = lane >> 4;
  const int l15  = lane & 15;
  const int x7   = l15 & 7;

  // XCD-grouped block swizzle (256 = 8*32, bijective): same-XCD blocks share A-panels
  const int lin = blockIdx.x;
  const int swz = ((lin & 7) << 5) | (lin >> 3);
  const int m0  = (swz >> 4) * 256;
  const int n0s = (swz & 15) * 256;                 // stacked N coordinate
  const u16* Bp = (n0s < 2048) ? wqb + (long)n0s * K
                               : wkb + (long)(n0s - 2048) * K;
  u16* O = (n0s < 2048) ? q : k;
  const int n0o = n0s & 2047;                       // col base within output

  const int wm = (wave >> 2) * 128;                 // 0 / 128
  const int wn = (wave & 3) * 64;                   // 0 / 64 / 128 / 192

  // staging geometry: wave w covers rows w*32..w*32+31 of the 256-row tile;
  // instr j covers 8 rows. lane: lrow = lane>>3 (row-in-8), lu = lane&7 (16B unit).
  // source col pre-swizzled: unit = lu ^ (row&7) = lu ^ lrow.
  const int lrow = lane >> 3;
  const int lu   = lane & 7;
  const int sunit = (lu ^ lrow) << 3;               // elems
  const u16* Ag = Ap + (long)(m0 + wave * 32 + lrow) * K + sunit;
  const u16* Bg = Bp + (long)(wave * 32 + lrow) * K + sunit;
  const int slds = wave * 2048;                     // wave's LDS region (elems)

  const f32x4 zero = {0.f, 0.f, 0.f, 0.f};
  f32x4 acc[8][4];
#pragma unroll
  for (int i = 0; i < 8; ++i)
#pragma unroll
    for (int j = 0; j < 4; ++j) acc[i][j] = zero;

  // prologue: stage tile 0 into buf0, drain, barrier
#pragma unroll
  for (int j = 0; j < 4; ++j) gl16(Ag + (long)j * 8 * K, &As[0][slds + j * 512]);
#pragma unroll
  for (int j = 0; j < 4; ++j) gl16(Bg + (long)j * 8 * K, &Bs[0][slds + j * 512]);
  VWAIT(0); SBAR();

  int cur = 0;
#pragma unroll 1
  for (int it = 0; it < 32; ++it) {
    const long kn = (long)(it + 1) * 64;            // next K-tile offset
    const bool hasNext = (it < 31);
    const u16* Ac = As[cur];
    const u16* Bc = Bs[cur];
    u16* An = As[cur ^ 1];
    u16* Bn = Bs[cur ^ 1];

    // ---- phase 0: bf[4][2] + af(0,1); stage A(next); MFMA m0,m1 ----
    short8 bf[4][2];
#pragma unroll
    for (int nf = 0; nf < 4; ++nf)
#pragma unroll
      for (int ks = 0; ks < 2; ++ks)
        bf[nf][ks] = *(const short8*)&Bc[(wn + nf * 16 + l15) * 64 + ((((ks << 2) + quad) ^ x7) << 3)];
    {
      short8 af[2][2];
#pragma unroll
      for (int mi = 0; mi < 2; ++mi)
#pragma unroll
        for (int ks = 0; ks < 2; ++ks)
          af[mi][ks] = *(const short8*)&Ac[(wm + mi * 16 + l15) * 64 + ((((ks << 2) + quad) ^ x7) << 3)];
      if (hasNext) {
#pragma unroll
        for (int j = 0; j < 4; ++j) gl16(Ag + kn + (long)j * 8 * K, &An[slds + j * 512]);
      }
      __builtin_amdgcn_s_setprio(1);
#pragma unroll
      for (int ks = 0; ks < 2; ++ks)
#pragma unroll
        for (int mi = 0; mi < 2; ++mi)
#pragma unroll
          for (int nf = 0; nf < 4; ++nf)
            acc[mi][nf] = __builtin_amdgcn_mfma_f32_16x16x32_bf16(af[mi][ks], bf[nf][ks], acc[mi][nf], 0, 0, 0);
      __builtin_amdgcn_s_setprio(0);
    }
    SBAR();

    // ---- phases 1..3: af(2mp, 2mp+1); ph1 stages B(next) ----
#pragma unroll
    for (int mp = 1; mp < 4; ++mp) {
      short8 af[2][2];
#pragma unroll
      for (int mi = 0; mi < 2; ++mi)
#pragma unroll
        for (int ks = 0; ks < 2; ++ks)
          af[mi][ks] = *(const short8*)&Ac[(wm + (mp * 2 + mi) * 16 + l15) * 64 + ((((ks << 2) + quad) ^ x7) << 3)];
      if (mp == 1 && hasNext) {
#pragma unroll
        for (int j = 0; j < 4; ++j) gl16(Bg + kn + (long)j * 8 * K, &Bn[slds + j * 512]);
      }
      __builtin_amdgcn_s_setprio(1);
#pragma unroll
      for (int ks = 0; ks < 2; ++ks)
#pragma unroll
        for (int mi = 0; mi < 2; ++mi)
#pragma unroll
          for (int nf = 0; nf < 4; ++nf)
            acc[mp * 2 + mi][nf] = __builtin_amdgcn_mfma_f32_16x16x32_bf16(af[mi][ks], bf[nf][ks], acc[mp * 2 + mi][nf], 0, 0, 0);
      __builtin_amdgcn_s_setprio(0);
      if (mp == 3) VWAIT(0);          // next tile fully landed (2-4 phases of cover)
      SBAR();
    }
    cur ^= 1;
  }

  // ---- epilogue: C/D layout col = lane&15, row = quad*4 + reg (verified m89/m91) ----
#pragma unroll
  for (int mf = 0; mf < 8; ++mf) {
    const int row0 = m0 + wm + mf * 16 + quad * 4;
#pragma unroll
    for (int nf = 0; nf < 4; ++nf) {
      const int col = n0o + wn + nf * 16 + l15;
#pragma unroll
      for (int r = 0; r < 4; ++r)
        O[(long)(row0 + r) * 2048 + col] = f2bf(flushv(acc[mf][nf][r], 7777.f));
    }
  }
}

// ================= 128^2 GEMM core (R8-verified: swizzled + counted vmcnt) =================
template <bool OF>
__device__ __forceinline__ void gemm_core(
    const u16* __restrict__ Ap, const u16* __restrict__ Bp,
    void* __restrict__ O, int m0, int n0, int N, float sentinel)
{
  __shared__ __align__(16) u16 As[2][128 * 32];
  __shared__ __align__(16) u16 Bs[2][128 * 32];
  constexpr int K = 2048;

  const int tid  = threadIdx.x;
  const int wave = tid >> 6;
  const int lane = tid & 63;
  const int quad = lane >> 4;
  const int l15  = lane & 15;

  const int wm = (wave >> 1) * 64;
  const int wn = (wave & 1) * 64;

  const int srow = lane >> 2;
  const int su   = lane & 3;
  const int r0   = wave * 32 + srow;
  const int csw  = ((su ^ ((r0 >> 1) & 3)) << 3);
  const u16* Ag0 = Ap + (long)(m0 + r0) * K + csw;
  const u16* Ag1 = Ag0 + 16 * (long)K;
  const u16* Bg0 = Bp + (long)(n0 + r0) * K + csw;
  const u16* Bg1 = Bg0 + 16 * (long)K;
  const int sl0 = (wave * 2 + 0) * 512;
  const int sl1 = (wave * 2 + 1) * 512;

  const int xsw = ((l15 >> 1) & 3) << 3;

  const f32x4 zero = {0.f, 0.f, 0.f, 0.f};
  f32x4 acc[4][4];
#pragma unroll
  for (int i = 0; i < 4; ++i)
#pragma unroll
    for (int j = 0; j < 4; ++j) acc[i][j] = zero;

  auto STAGE = [&](int bs, int k0) {
    gl16(Ag0 + k0, &As[bs][sl0]); gl16(Ag1 + k0, &As[bs][sl1]);
    gl16(Bg0 + k0, &Bs[bs][sl0]); gl16(Bg1 + k0, &Bs[bs][sl1]);
  };
  auto COMPUTE = [&](const u16* Ab, const u16* Bb) {
    short8 af[4], bf[4];
#pragma unroll
    for (int i = 0; i < 4; ++i)
      af[i] = *(const short8*)&Ab[(wm + i * 16 + l15) * 32 + ((quad << 3) ^ xsw)];
#pragma unroll
    for (int j = 0; j < 4; ++j)
      bf[j] = *(const short8*)&Bb[(wn + j * 16 + l15) * 32 + ((quad << 3) ^ xsw)];
#pragma unroll
    for (int i = 0; i < 4; ++i)
#pragma unroll
      for (int j = 0; j < 4; ++j)
        acc[i][j] = __builtin_amdgcn_mfma_f32_16x16x32_bf16(af[i], bf[j], acc[i][j], 0, 0, 0);
  };

  STAGE(0, 0);

#pragma unroll 1
  for (int k0 = 0; k0 < K; k0 += 64) {
    STAGE(1, k0 + 32);
    VWAIT(4); SBAR();
    COMPUTE(As[0], Bs[0]);
    SBAR();

    if (k0 + 64 < K) { STAGE(0, k0 + 64); VWAIT(4); }
    else             { VWAIT(0); }
    SBAR();
    COMPUTE(As[1], Bs[1]);
    SBAR();
  }

#pragma unroll
  for (int i = 0; i < 4; ++i) {
    const int row0 = m0 + wm + i * 16 + quad * 4;
#pragma unroll
    for (int j = 0; j < 4; ++j) {
      const int col = n0 + wn + j * 16 + l15;
#pragma unroll
      for (int r = 0; r < 4; ++r) {
        const float val = flushv(acc[i][j][r], sentinel);
        if constexpr (OF)
          ((float*)O)[(long)(row0 + r) * N + col] = val;
        else
          ((u16*)O)[(long)(row0 + r) * N + col] = f2bf(val);
      }
    }
  }
}

// V^T = Wv @ xb^T : C[2048 d][4096 tok]
__global__ __launch_bounds__(256) void gemm_vt(
    const u16* __restrict__ wvb, const u16* __restrict__ xb, u16* __restrict__ v)
{
  const int r = blockIdx.x;   // 512
  gemm_core<false>(wvb, xb, v, (r >> 5) * 128, (r & 31) * 128, 4096, 7777.f);
}

// output projection: [4096][2048] fp32 = ao @ Wo^T
__global__ __launch_bounds__(256) void gemm_proj(
    const u16* __restrict__ ao, const u16* __restrict__ wob, float* __restrict__ out)
{
  const int r = blockIdx.x;   // 512
  gemm_core<true>(ao, wob, out, (r >> 4) * 128, (r & 15) * 128, 2048, 5555.f);
}

// ================= legacy GEMM (fp32-staging) — fallback path only =================
template <bool AF, bool WF, bool OF>
__global__ __launch_bounds__(256) void gemm_bt(
    const void* __restrict__ Ap,
    const void* __restrict__ Wp0, const void* __restrict__ Wp1, const void* __restrict__ Wp2,
    void* __restrict__ O0, void* __restrict__ O1, void* __restrict__ O2,
    int M, int N, int K, float sentinel)
{
  __shared__ __align__(16) u16 As[128 * 32];
  __shared__ __align__(16) u16 Bs[128 * 32];

  const void* Wp; void* O;
  if (blockIdx.z == 0)      { Wp = Wp0; O = O0; }
  else if (blockIdx.z == 1) { Wp = Wp1; O = O1; }
  else                      { Wp = Wp2; O = O2; }

  const float* Af = (const float*)Ap;  const u16* Ab = (const u16*)Ap;
  const float* Wf = (const float*)Wp;  const u16* Wb = (const u16*)Wp;

  const int tid  = threadIdx.x;
  const int wave = tid >> 6;
  const int lane = tid & 63;
  const int quad = lane >> 4;
  const int l15  = lane & 15;

  const int m0 = blockIdx.y * 128;
  const int n0 = blockIdx.x * 128;
  const int wm = (wave >> 1) * 64;
  const int wn = (wave & 1) * 64;

  const int e0 = wave * 1024 + lane * 8;
  const int e1 = e0 + 512;
  const int r0 = e0 >> 5, c0 = e0 & 31;
  const int r1 = e1 >> 5, c1 = e1 & 31;

  const long aoff0 = (long)(m0 + r0) * K + c0;
  const long aoff1 = (long)(m0 + r1) * K + c1;
  const long boff0 = (long)(n0 + r0) * K + c0;
  const long boff1 = (long)(n0 + r1) * K + c1;

  const f32x4 zero = {0.f, 0.f, 0.f, 0.f};
  f32x4 acc[4][4];
#pragma unroll
  for (int i = 0; i < 4; ++i)
#pragma unroll
    for (int j = 0; j < 4; ++j) acc[i][j] = zero;

  for (int k0 = 0; k0 < K; k0 += 32) {
    short8 a0, a1, b0, b1;
    if constexpr (AF) {
      a0 = ld8f(Af + aoff0 + k0);
      a1 = ld8f(Af + aoff1 + k0);
    } else {
      a0 = *(const short8*)(Ab + aoff0 + k0);
      a1 = *(const short8*)(Ab + aoff1 + k0);
    }
    if constexpr (WF) {
      b0 = ld8f(Wf + boff0 + k0);
      b1 = ld8f(Wf + boff1 + k0);
    } else {
      b0 = *(const short8*)(Wb + boff0 + k0);
      b1 = *(const short8*)(Wb + boff1 + k0);
    }

    __syncthreads();
    *(short8*)&As[e0] = a0;
    *(short8*)&As[e1] = a1;
    *(short8*)&Bs[e0] = b0;
    *(short8*)&Bs[e1] = b1;
    __syncthreads();

    short8 af[4], bf[4];
#pragma unroll
    for (int i = 0; i < 4; ++i)
      af[i] = *(const short8*)&As[(wm + i * 16 + l15) * 32 + quad * 8];
#pragma unroll
    for (int j = 0; j < 4; ++j)
      bf[j] = *(const short8*)&Bs[(wn + j * 16 + l15) * 32 + quad * 8];
#pragma unroll
    for (int i = 0; i < 4; ++i)
#pragma unroll
      for (int j = 0; j < 4; ++j)
        acc[i][j] = __builtin_amdgcn_mfma_f32_16x16x32_bf16(af[i], bf[j], acc[i][j], 0, 0, 0);
  }

#pragma unroll
  for (int i = 0; i < 4; ++i) {
    const int row0 = m0 + wm + i * 16 + quad * 4;
#pragma unroll
    for (int j = 0; j < 4; ++j) {
      const int col = n0 + wn + j * 16 + l15;
#pragma unroll
      for (int r = 0; r < 4; ++r) {
        const float val = flushv(acc[i][j][r], sentinel);
        if constexpr (OF)
          ((float*)O)[(long)(row0 + r) * N + col] = val;
        else
          ((u16*)O)[(long)(row0 + r) * N + col] = f2bf(val);
      }
    }
  }
}

// ================= RoPE (chunk-half), in-place, vectorized x8 (G13) =================
__global__ __launch_bounds__(256) void rope_kernel(u16* __restrict__ Q, u16* __restrict__ K)
{
  int t = blockIdx.x * 256 + threadIdx.x;
  const int per = 524288;              // 65536 rows * 8 i-groups
  u16* P = Q;
  if (t >= per) { P = K; t -= per; }
  const int i8  = t & 7;
  const int row = t >> 3;              // (b*2048 + s)*16 + h
  const int s   = (row >> 4) & 2047;
  const long off = (long)row * 128 + i8 * 8;

  short8 va = *(const short8*)&P[off];
  short8 vb = *(const short8*)&P[off + 64];

  const float fs = (float)s;
  float invf = __expf((float)(i8 * 8) * -0.14391156831212787f);  // 10000^(-i/64)
  const float step = 0.86596432336f;                             // 10000^(-1/64)
#pragma unroll
  for (int j = 0; j < 8; ++j) {
    float sn, cs;
    __sincosf(fs * invf, &sn, &cs);
    const float q1 = bf2f((u16)va[j]);
    const float q2 = bf2f((u16)vb[j]);
    va[j] = (short)f2bf(q1 * cs - q2 * sn);
    vb[j] = (short)f2bf(q1 * sn + q2 * cs);
    invf *= step;
  }
  *(short8*)&P[off]      = va;
  *(short8*)&P[off + 64] = vb;
}

// ================= causal flash attention (LDS-staged, lockstep, 2-phase) =================
__global__ __launch_bounds__(256, 4) void attn_kernel(
    const u16* __restrict__ Q, const u16* __restrict__ K,
    const u16* __restrict__ VT, u16* __restrict__ AO)
{
  __shared__ __align__(16) u16 Kb[2][4096];  // [32 key][128 d], unit^=(row&7) swizzle
  __shared__ __align__(16) u16 Vb[2][4096];  // [128 d][32 tok], unit^=((row>>1)&3)

  const int tid  = threadIdx.x;
  const int wave = tid >> 6;
  const int lane = tid & 63;
  const int quad = lane >> 4;
  const int l15  = lane & 15;

  const int lin = blockIdx.x;                 // 0..1023
  const int xcd = lin & 7;
  const int hi  = lin >> 8;                   // 0..3
  const int g   = (lin >> 3) & 31;            // 0..31
  const int qb  = (hi & 1) ? (31 - g) : g;
  const int bh  = (xcd << 2) | hi;
  const int b   = bh >> 4;
  const int h   = bh & 15;

  const long base = (long)b * 2048 * 2048 + (long)h * 128;
  const long vtb  = (long)h * 128 * 4096 + (long)b * 2048;
  const int q0w = qb * 64 + wave * 16;
  const int qi  = q0w + l15;

  const u16* Kp0 = K + base;
  const u16* Vp0 = VT + vtb;

  auto STAGE = [&](int bs, int jb) {
#pragma unroll
    for (int gi = 0; gi < 2; ++gi) {
      const int slot = wave * 2 + gi;
      {
        const int row = slot * 4 + (lane >> 4);
        const int su  = lane & 15;
        gl16(Kp0 + (long)(jb * 32 + row) * 2048 + ((su ^ (row & 7)) << 3),
             &Kb[bs][slot * 512]);
      }
      {
        const int row = slot * 16 + (lane >> 2);
        const int su  = lane & 3;
        gl16(Vp0 + (long)row * 4096 + jb * 32 + ((su ^ ((row >> 1) & 3)) << 3),
             &Vb[bs][slot * 512]);
      }
    }
  };

  short8 qa[4];
#pragma unroll
  for (int c = 0; c < 4; ++c)
    qa[c] = *(const short8*)&Q[base + (long)(q0w + l15) * 2048 + c * 32 + quad * 8];

  const f32x4 zero = {0.f, 0.f, 0.f, 0.f};
  f32x4 o[8];
#pragma unroll
  for (int c = 0; c < 8; ++c) o[c] = zero;

  float mreg = -1e30f, lreg = 0.f;
  const float scale = 0.08838834764831845f;  // 1/sqrt(128)

  const int njb_blk = qb * 2 + 2;
  const int njb_w   = qb * 2 + 1 + (wave >> 1);

  STAGE(0, 0);
  __syncthreads();

  const int xorK = l15 & 7;
  const int xorV = (l15 >> 1) & 3;

  int cur = 0;
  for (int jb = 0; jb < njb_blk; ++jb) {
    if (jb + 1 < njb_blk) STAGE(cur ^ 1, jb + 1);

    if (jb < njb_w) {
      const int j0 = jb * 32;

      f32x4 s0T = zero, s1T = zero;
#pragma unroll
      for (int c = 0; c < 4; ++c) {
        const short8 kA = *(const short8*)&Kb[cur][l15 * 128 + (((c * 4 + quad) ^ xorK) << 3)];
        const short8 kB2 = *(const short8*)&Kb[cur][(l15 + 16) * 128 + (((c * 4 + quad) ^ xorK) << 3)];
        s0T = __builtin_amdgcn_mfma_f32_16x16x32_bf16(kA, qa[c], s0T, 0, 0, 0);
        s1T = __builtin_amdgcn_mfma_f32_16x16x32_bf16(kB2, qa[c], s1T, 0, 0, 0);
      }

      float sv0[4], sv1[4];
      float pmax = -1e30f;
      if (j0 + 31 > q0w) {
#pragma unroll
        for (int r = 0; r < 4; ++r) {
          const int k0i = j0 + quad * 4 + r;
          float s0 = s0T[r] * scale; if (k0i > qi)      s0 = -1e30f;
          float s1 = s1T[r] * scale; if (k0i + 16 > qi) s1 = -1e30f;
          sv0[r] = s0; sv1[r] = s1;
          pmax = fmaxf(pmax, fmaxf(s0, s1));
        }
      } else {
#pragma unroll
        for (int r = 0; r < 4; ++r) {
          sv0[r] = s0T[r] * scale;
          sv1[r] = s1T[r] * scale;
          pmax = fmaxf(pmax, fmaxf(sv0[r], sv1[r]));
        }
      }
      pmax = fmaxf(pmax, __shfl_xor(pmax, 16, 64));
      pmax = fmaxf(pmax, __shfl_xor(pmax, 32, 64));
      const float mprev = mreg;
      const float mnew  = fmaxf(mprev, pmax);
      const float alpha = __expf(mprev - mnew);
      float psum = 0.f;
#pragma unroll
      for (int r = 0; r < 4; ++r) {
        sv0[r] = __expf(sv0[r] - mnew);
        sv1[r] = __expf(sv1[r] - mnew);
        psum += sv0[r] + sv1[r];
      }
      psum += __shfl_xor(psum, 16, 64);
      psum += __shfl_xor(psum, 32, 64);
      lreg = lreg * alpha + psum;
      mreg = mnew;

      int w0, w1, w2, w3;
      asm("v_cvt_pk_bf16_f32 %0, %1, %2" : "=v"(w0) : "v"(sv0[0]), "v"(sv0[1]));
      asm("v_cvt_pk_bf16_f32 %0, %1, %2" : "=v"(w1) : "v"(sv0[2]), "v"(sv0[3]));
      asm("v_cvt_pk_bf16_f32 %0, %1, %2" : "=v"(w2) : "v"(sv1[0]), "v"(sv1[1]));
      asm("v_cvt_pk_bf16_f32 %0, %1, %2" : "=v"(w3) : "v"(sv1[2]), "v"(sv1[3]));
      const int srcA = l15 + ((quad & 1) << 5);
      const int srcB = srcA + 16;
      const int a0 = __shfl(w0, srcA, 64), a1 = __shfl(w1, srcA, 64);
      const int a2 = __shfl(w0, srcB, 64), a3 = __shfl(w1, srcB, 64);
      const int h0 = __shfl(w2, srcA, 64), h1 = __shfl(w3, srcA, 64);
      const int h2 = __shfl(w2, srcB, 64), h3 = __shfl(w3, srcB, 64);
      const bool hiq = quad >= 2;
      i32x4 pt;
      pt[0] = hiq ? h0 : a0;
      pt[1] = hiq ? h1 : a1;
      pt[2] = hiq ? h2 : a2;
      pt[3] = hiq ? h3 : a3;
      const short8 pa = *(const short8*)&pt;

      float av[4];
#pragma unroll
      for (int r = 0; r < 4; ++r) av[r] = __shfl(alpha, quad * 4 + r, 64);
#pragma unroll
      for (int c = 0; c < 8; ++c) {
        o[c][0] *= av[0]; o[c][1] *= av[1]; o[c][2] *= av[2]; o[c][3] *= av[3];
      }

#pragma unroll
      for (int c = 0; c < 8; ++c) {
        const short8 vf = *(const short8*)&Vb[cur][(c * 16 + l15) * 32 + ((quad ^ xorV) << 3)];
        o[c] = __builtin_amdgcn_mfma_f32_16x16x32_bf16(pa, vf, o[c], 0, 0, 0);
      }
    }

    __syncthreads();
    cur ^= 1;
  }

#pragma unroll
  for (int r = 0; r < 4; ++r) {
    const float lr  = __shfl(lreg, quad * 4 + r, 64);
    const float inv = 1.0f / lr;
    const long rowoff = base + (long)(q0w + quad * 4 + r) * 2048;
#pragma unroll
    for (int c = 0; c < 8; ++c)
      AO[rowoff + c * 16 + l15] = f2bf(flushv(o[c][r] * inv, 9999.f));
  }
}

// ================= diagnostic fill =================
__global__ __launch_bounds__(256) void fill_kernel(float* __restrict__ out, long n, float v)
{
  const long t = (long)blockIdx.x * 256 + threadIdx.x;
  if (t < n) out[t] = v;
}

// ================= launch =================
extern "C" void kernel_launch(void* const* d_in, const int* in_sizes, int n_in,
                              void* d_out, int out_size, void* d_ws, size_t ws_size,
                              hipStream_t stream)
{
  // Inputs fp32 (x, Wq, Wk, Wv, Wo); OUTPUT fp32 (reference dtype).
  const float* x  = (const float*)d_in[0];
  const float* Wq = (const float*)d_in[1];
  const float* Wk = (const float*)d_in[2];
  const float* Wv = (const float*)d_in[3];
  const float* Wo = (const float*)d_in[4];
  float* out = (float*)d_out;

  const long QSZ = (long)2 * 2048 * 2048;  // 8388608 elems
  const long WSZ = QSZ / 2;                // 2048*2048 weight elems

  u16* ws = (u16*)d_ws;
  u16* q  = ws;            // bf16 internal
  u16* k  = ws + QSZ;
  u16* v  = ws + 2 * QSZ;  // V^T: [2048 d][4096 tok]
  u16* ao = q;             // attention output in-place over q (partition-safe)

  if (ws_size >= (size_t)6 * QSZ * sizeof(u16)) {
    // ---- fast path: bf16 pre-convert + 8-phase QK GEMM + swizzled 128^2 VT/proj ----
    u16* xb  = ws + 3 * QSZ;        // x as bf16 [4096][2048]
    u16* wqb = ws + 4 * QSZ;
    u16* wkb = wqb + WSZ;
    u16* wvb = wqb + 2 * WSZ;
    u16* wob = wqb + 3 * WSZ;

    cvt_all<<<12288, 256, 0, stream>>>(x, Wq, Wk, Wv, Wo, xb, wqb, wkb, wvb, wob);
    gemm_qk8<<<256, 512, 0, stream>>>(xb, wqb, wkb, q, k);
    gemm_vt<<<512, 256, 0, stream>>>(wvb, xb, v);
    rope_kernel<<<4096, 256, 0, stream>>>(q, k);
    attn_kernel<<<1024, 256, 0, stream>>>(q, k, v, ao);
    gemm_proj<<<512, 256, 0, stream>>>(ao, wob, out);
    return;
  }

  // ---- fallback: R5 path (fp32-staging GEMMs), needs 48 MB ----
  if (ws_size < (size_t)3 * QSZ * sizeof(u16)) {
    fill_kernel<<<(int)((QSZ + 255) / 256), 256, 0, stream>>>(out, QSZ, 1111.f);
    return;
  }

  gemm_bt<true, true, false><<<dim3(16, 32, 2), 256, 0, stream>>>(
      x, Wq, Wk, Wk, q, k, k, 4096, 2048, 2048, 7777.f);
  gemm_bt<true, true, false><<<dim3(32, 16, 1), 256, 0, stream>>>(
      Wv, x, x, x, v, v, v, 2048, 4096, 2048, 7777.f);
  rope_kernel<<<4096, 256, 0, stream>>>(q, k);
  attn_kernel<<<1024, 256, 0, stream>>>(q, k, v, ao);
  gemm_bt<false, true, true><<<dim3(16, 32, 1), 256, 0, stream>>>(
      ao, Wo, Wo, Wo, out, out, out, 4096, 2048, 2048, 5555.f);
}

// Round 10
// 377.490 us; speedup vs baseline: 1.8925x; 1.0327x over previous
//
#include <hip/hip_runtime.h>

typedef unsigned short u16;
typedef __attribute__((ext_vector_type(8))) short short8;
typedef __attribute__((ext_vector_type(4))) float f32x4;
typedef __attribute__((ext_vector_type(4))) int i32x4;

// ---------- bf16 helpers (RNE) ----------
__device__ __forceinline__ float bf2f(u16 u) {
  union { unsigned u; float f; } v; v.u = ((unsigned)u) << 16; return v.f;
}
__device__ __forceinline__ u16 f2bf(float f) {
  union { float f; unsigned u; } v; v.f = f;
  unsigned r = (v.u + 0x7FFFu + ((v.u >> 16) & 1u)) >> 16;
  return (u16)r;
}
__device__ __forceinline__ float flushv(float t, float sentinel) {
  if (t != t || fabsf(t) > 3.0e38f) return sentinel;
  return t;
}
// load 8 fp32 and convert to bf16x8
__device__ __forceinline__ short8 ld8f(const float* p) {
  const float4 f0 = *(const float4*)p;
  const float4 f1 = *(const float4*)(p + 4);
  short8 r;
  r[0] = (short)f2bf(f0.x); r[1] = (short)f2bf(f0.y);
  r[2] = (short)f2bf(f0.z); r[3] = (short)f2bf(f0.w);
  r[4] = (short)f2bf(f1.x); r[5] = (short)f2bf(f1.y);
  r[6] = (short)f2bf(f1.z); r[7] = (short)f2bf(f1.w);
  return r;
}

// async global->LDS, 16B per lane; LDS dest = wave-uniform base + lane*16 (linear)
__device__ __forceinline__ void gl16(const u16* g, u16* l) {
  __builtin_amdgcn_global_load_lds(
      (const __attribute__((address_space(1))) void*)g,
      (__attribute__((address_space(3))) void*)l, 16, 0, 0);
}

// counted vmcnt wait (asm: compiler cannot fold it into a full drain) + IR fence
#define VWAIT(N) do { \
  asm volatile("s_waitcnt vmcnt(" #N ")" ::: "memory"); \
  __builtin_amdgcn_sched_barrier(0); } while (0)
// raw barrier WITHOUT vmcnt drain (T4: loads stay in flight across it)
#define SBAR() do { __builtin_amdgcn_sched_barrier(0); \
                    __builtin_amdgcn_s_barrier(); \
                    __builtin_amdgcn_sched_barrier(0); } while (0)

// ================= fp32 -> bf16 conversion (single pass, 5 tensors) =================
__global__ __launch_bounds__(256) void cvt_all(
    const float* __restrict__ x,
    const float* __restrict__ Wq, const float* __restrict__ Wk,
    const float* __restrict__ Wv, const float* __restrict__ Wo,
    u16* __restrict__ xb, u16* __restrict__ wqb, u16* __restrict__ wkb,
    u16* __restrict__ wvb, u16* __restrict__ wob)
{
  const int bid = blockIdx.x;
  const float* s; u16* d; long t;
  if (bid < 8192) {
    const int which = bid >> 11;
    t = (long)(bid & 2047) * 256 + threadIdx.x;
    if (which == 0)      { s = Wq; d = wqb; }
    else if (which == 1) { s = Wk; d = wkb; }
    else if (which == 2) { s = Wv; d = wvb; }
    else                 { s = Wo; d = wob; }
  } else {
    s = x; d = xb;
    t = (long)(bid - 8192) * 256 + threadIdx.x;
  }
  *(short8*)&d[t * 8] = ld8f(s + t * 8);
}

// ================= depth-2 256^2 GEMM + fused RoPE: [Q|K] = rope(xb @ [Wq;Wk]^T) =================
// M=4096 (tok), N=4096 (stacked Q|K), K=2048, BK=32, 64 K-tiles. Grid 256 = 1 block/CU.
// 512 thr (8 waves, 2Mx4N). LDS 128KB: 4-slot ring x (A 16K + B 16K).
// Depth-2 counted pipeline (T4: vmcnt NEVER 0 in main loop):
//   iter it: VWAIT(4) [tile it resident; tile it+1's 4 loads stay in flight] ; SBAR
//     ph0: ds bf[0..3]+af[0..3] | stage-A(it+2 -> ring[(it+2)&3]) | 16 MFMA | SBAR
//     ph1: ds af[4..7]          | stage-B(it+2)                   | 16 MFMA
//   -> each stage gets ~2 full iterations (~600cy) of cover (L3-latency safe).
//   WAR: ring[(it+2)&3] last read at iter it-2, two barriers ago. Last tile peeled (VWAIT(0)).
// Swizzle (rule #21 both-sides): src unit ^= (row>>1)&3 (= (lane>>3)&3 at stage,
// (l15>>1)&3 at read) -> 8 16B-groups x 8 lanes = optimal (R8-verified, 0 conflicts).
// Wave-N remap for RoPE pairing: wave covers {h*32..+31} u {h*32+64..+95} of a 128-d
// head group -> acc[mf][nf] pairs with acc[mf][nf+2] (d, d+64). RoPE applied to the
// fp32 accumulator in the epilogue (one fewer bf16 rounding than a separate pass).
__global__ __launch_bounds__(512, 2) void gemm_qk8(
    const u16* __restrict__ Ap, const u16* __restrict__ wqb, const u16* __restrict__ wkb,
    u16* __restrict__ q, u16* __restrict__ kout)
{
  __shared__ __align__(16) u16 As[4][256 * 32];
  __shared__ __align__(16) u16 Bs[4][256 * 32];
  constexpr int K = 2048;

  const int tid  = threadIdx.x;
  const int wave = tid >> 6;           // 0..7
  const int lane = tid & 63;
  const int quad = lane >> 4;
  const int l15  = lane & 15;

  // XCD clustering 4m x 8n (12MB/XCD working set; bijective over 256 blocks)
  const int lin = blockIdx.x;
  const int xcd = lin & 7, pos = lin >> 3;
  const int m0  = ((xcd >> 1) * 4 + (pos >> 3)) * 256;
  const int n0s = ((xcd & 1) * 8 + (pos & 7)) * 256;
  const u16* Bp = (n0s < 2048) ? wqb + (long)n0s * K : wkb + (long)(n0s - 2048) * K;
  u16* O = (n0s < 2048) ? q : kout;
  const int n0o = n0s & 2047;

  const int wm   = (wave >> 2) * 128;  // 0 / 128
  const int wn_g = (wave & 2) * 64;    // 0 / 128  (which 128-d head group)
  const int wn_h = (wave & 1) * 32;    // 0 / 32   (which 32-col half)

  // staging: wave covers tile rows wave*32..+31; instr j in {0,1} covers 16 rows.
  // lane: row-in-16 = lane>>2, unit = lane&3; src col pre-swizzled by (row>>1)&3 = (lane>>3)&3.
  const int lrow  = lane >> 2;
  const int sunit = ((lane & 3) ^ ((lane >> 3) & 3)) << 3;
  const u16* Ag = Ap + (long)(m0 + wave * 32 + lrow) * K + sunit;
  const u16* Bg = Bp + (long)(wave * 32 + lrow) * K + sunit;
  const int slds = wave * 1024;        // wave's 32 rows x 32 elems

  const int xr = (l15 >> 1) & 3;       // ds_read swizzle

  const f32x4 zero = {0.f, 0.f, 0.f, 0.f};
  f32x4 acc[8][4];
#pragma unroll
  for (int i = 0; i < 8; ++i)
#pragma unroll
    for (int j = 0; j < 4; ++j) acc[i][j] = zero;

  auto STA = [&](int buf, int kt) {
    gl16(Ag + (long)kt * 32,                &As[buf][slds]);
    gl16(Ag + (long)kt * 32 + (long)16 * K, &As[buf][slds + 512]);
  };
  auto STB = [&](int buf, int kt) {
    gl16(Bg + (long)kt * 32,                &Bs[buf][slds]);
    gl16(Bg + (long)kt * 32 + (long)16 * K, &Bs[buf][slds + 512]);
  };

  // prologue: tiles 0 and 1 (oldest 4 loads = tile 0)
  STA(0, 0); STB(0, 0);
  STA(1, 1); STB(1, 1);

#pragma unroll 1
  for (int it = 0; it < 63; ++it) {
    const int cur = it & 3;
    const int nxt = (it + 2) & 3;
    const u16* Ac = As[cur];
    const u16* Bc = Bs[cur];
    const bool st = (it + 2 < 64);

    VWAIT(4); SBAR();                  // tile it collectively resident; it+1 in flight

    // ---- ph0: bf[0..3] + af[0..3]; stage A(it+2); MFMA mf0..3 ----
    short8 bf[4], af[4];
#pragma unroll
    for (int nf = 0; nf < 4; ++nf) {
      const int bcol = wn_g + wn_h + (nf >> 1) * 64 + (nf & 1) * 16 + l15;
      bf[nf] = *(const short8*)&Bc[bcol * 32 + ((quad ^ xr) << 3)];
    }
#pragma unroll
    for (int mi = 0; mi < 4; ++mi)
      af[mi] = *(const short8*)&Ac[(wm + mi * 16 + l15) * 32 + ((quad ^ xr) << 3)];
    if (st) STA(nxt, it + 2);
    __builtin_amdgcn_s_setprio(1);
#pragma unroll
    for (int mi = 0; mi < 4; ++mi)
#pragma unroll
      for (int nf = 0; nf < 4; ++nf)
        acc[mi][nf] = __builtin_amdgcn_mfma_f32_16x16x32_bf16(af[mi], bf[nf], acc[mi][nf], 0, 0, 0);
    __builtin_amdgcn_s_setprio(0);
    SBAR();

    // ---- ph1: af[4..7]; stage B(it+2); MFMA mf4..7 ----
#pragma unroll
    for (int mi = 0; mi < 4; ++mi)
      af[mi] = *(const short8*)&Ac[(wm + (mi + 4) * 16 + l15) * 32 + ((quad ^ xr) << 3)];
    if (st) STB(nxt, it + 2);
    __builtin_amdgcn_s_setprio(1);
#pragma unroll
    for (int mi = 0; mi < 4; ++mi)
#pragma unroll
      for (int nf = 0; nf < 4; ++nf)
        acc[mi + 4][nf] = __builtin_amdgcn_mfma_f32_16x16x32_bf16(af[mi], bf[nf], acc[mi + 4][nf], 0, 0, 0);
    __builtin_amdgcn_s_setprio(0);
  }

  // ---- peeled last tile (63, ring slot 3): only its 4 loads remain ----
  {
    VWAIT(0); SBAR();
    const u16* Ac = As[3];
    const u16* Bc = Bs[3];
    short8 bf[4], af[4];
#pragma unroll
    for (int nf = 0; nf < 4; ++nf) {
      const int bcol = wn_g + wn_h + (nf >> 1) * 64 + (nf & 1) * 16 + l15;
      bf[nf] = *(const short8*)&Bc[bcol * 32 + ((quad ^ xr) << 3)];
    }
#pragma unroll
    for (int mi = 0; mi < 4; ++mi)
      af[mi] = *(const short8*)&Ac[(wm + mi * 16 + l15) * 32 + ((quad ^ xr) << 3)];
#pragma unroll
    for (int mi = 0; mi < 4; ++mi)
#pragma unroll
      for (int nf = 0; nf < 4; ++nf)
        acc[mi][nf] = __builtin_amdgcn_mfma_f32_16x16x32_bf16(af[mi], bf[nf], acc[mi][nf], 0, 0, 0);
#pragma unroll
    for (int mi = 0; mi < 4; ++mi)
      af[mi] = *(const short8*)&Ac[(wm + (mi + 4) * 16 + l15) * 32 + ((quad ^ xr) << 3)];
#pragma unroll
    for (int mi = 0; mi < 4; ++mi)
#pragma unroll
      for (int nf = 0; nf < 4; ++nf)
        acc[mi + 4][nf] = __builtin_amdgcn_mfma_f32_16x16x32_bf16(af[mi], bf[nf], acc[mi + 4][nf], 0, 0, 0);
  }

  // ---- epilogue: fused RoPE (chunk-half) + bf16 store ----
  // lane's d values (within 128-d head): nf=0 -> d0 = wn_h+l15, nf=1 -> d1 = d0+16 (both <64);
  // pair d+64 lives in acc[mf][nf+2]. angle = (tok mod 2048) * 10000^(-d/64).
  const float invf0 = __expf((float)(wn_h + l15) * -0.14391156831212787f);
  const float invf1 = __expf((float)(wn_h + 16 + l15) * -0.14391156831212787f);
#pragma unroll
  for (int mf = 0; mf < 8; ++mf) {
    const int row0 = m0 + wm + mf * 16 + quad * 4;
#pragma unroll
    for (int r = 0; r < 4; ++r) {
      const int tok = row0 + r;
      const float fs = (float)(tok & 2047);
      float sn0, cs0, sn1, cs1;
      __sincosf(fs * invf0, &sn0, &cs0);
      __sincosf(fs * invf1, &sn1, &cs1);
      const float a0 = acc[mf][0][r], c0 = acc[mf][2][r];
      const float a1 = acc[mf][1][r], c1 = acc[mf][3][r];
      const long rb = (long)tok * 2048 + n0o + wn_g + wn_h + l15;
      O[rb]      = f2bf(flushv(a0 * cs0 - c0 * sn0, 7777.f));
      O[rb + 64] = f2bf(flushv(a0 * sn0 + c0 * cs0, 7777.f));
      O[rb + 16] = f2bf(flushv(a1 * cs1 - c1 * sn1, 7777.f));
      O[rb + 80] = f2bf(flushv(a1 * sn1 + c1 * cs1, 7777.f));
    }
  }
}

// ================= 128^2 GEMM core (R8-verified: swizzled + counted vmcnt) =================
template <bool OF>
__device__ __forceinline__ void gemm_core(
    const u16* __restrict__ Ap, const u16* __restrict__ Bp,
    void* __restrict__ O, int m0, int n0, int N, float sentinel)
{
  __shared__ __align__(16) u16 As[2][128 * 32];
  __shared__ __align__(16) u16 Bs[2][128 * 32];
  constexpr int K = 2048;

  const int tid  = threadIdx.x;
  const int wave = tid >> 6;
  const int lane = tid & 63;
  const int quad = lane >> 4;
  const int l15  = lane & 15;

  const int wm = (wave >> 1) * 64;
  const int wn = (wave & 1) * 64;

  const int srow = lane >> 2;
  const int su   = lane & 3;
  const int r0   = wave * 32 + srow;
  const int csw  = ((su ^ ((r0 >> 1) & 3)) << 3);
  const u16* Ag0 = Ap + (long)(m0 + r0) * K + csw;
  const u16* Ag1 = Ag0 + 16 * (long)K;
  const u16* Bg0 = Bp + (long)(n0 + r0) * K + csw;
  const u16* Bg1 = Bg0 + 16 * (long)K;
  const int sl0 = (wave * 2 + 0) * 512;
  const int sl1 = (wave * 2 + 1) * 512;

  const int xsw = ((l15 >> 1) & 3) << 3;

  const f32x4 zero = {0.f, 0.f, 0.f, 0.f};
  f32x4 acc[4][4];
#pragma unroll
  for (int i = 0; i < 4; ++i)
#pragma unroll
    for (int j = 0; j < 4; ++j) acc[i][j] = zero;

  auto STAGE = [&](int bs, int k0) {
    gl16(Ag0 + k0, &As[bs][sl0]); gl16(Ag1 + k0, &As[bs][sl1]);
    gl16(Bg0 + k0, &Bs[bs][sl0]); gl16(Bg1 + k0, &Bs[bs][sl1]);
  };
  auto COMPUTE = [&](const u16* Ab, const u16* Bb) {
    short8 af[4], bf[4];
#pragma unroll
    for (int i = 0; i < 4; ++i)
      af[i] = *(const short8*)&Ab[(wm + i * 16 + l15) * 32 + ((quad << 3) ^ xsw)];
#pragma unroll
    for (int j = 0; j < 4; ++j)
      bf[j] = *(const short8*)&Bb[(wn + j * 16 + l15) * 32 + ((quad << 3) ^ xsw)];
#pragma unroll
    for (int i = 0; i < 4; ++i)
#pragma unroll
      for (int j = 0; j < 4; ++j)
        acc[i][j] = __builtin_amdgcn_mfma_f32_16x16x32_bf16(af[i], bf[j], acc[i][j], 0, 0, 0);
  };

  STAGE(0, 0);

#pragma unroll 1
  for (int k0 = 0; k0 < K; k0 += 64) {
    STAGE(1, k0 + 32);
    VWAIT(4); SBAR();
    COMPUTE(As[0], Bs[0]);
    SBAR();

    if (k0 + 64 < K) { STAGE(0, k0 + 64); VWAIT(4); }
    else             { VWAIT(0); }
    SBAR();
    COMPUTE(As[1], Bs[1]);
    SBAR();
  }

#pragma unroll
  for (int i = 0; i < 4; ++i) {
    const int row0 = m0 + wm + i * 16 + quad * 4;
#pragma unroll
    for (int j = 0; j < 4; ++j) {
      const int col = n0 + wn + j * 16 + l15;
#pragma unroll
      for (int r = 0; r < 4; ++r) {
        const float val = flushv(acc[i][j][r], sentinel);
        if constexpr (OF)
          ((float*)O)[(long)(row0 + r) * N + col] = val;
        else
          ((u16*)O)[(long)(row0 + r) * N + col] = f2bf(val);
      }
    }
  }
}

// V^T = Wv @ xb^T : C[2048 d][4096 tok]
__global__ __launch_bounds__(256) void gemm_vt(
    const u16* __restrict__ wvb, const u16* __restrict__ xb, u16* __restrict__ v)
{
  const int r = blockIdx.x;   // 512
  gemm_core<false>(wvb, xb, v, (r >> 5) * 128, (r & 31) * 128, 4096, 7777.f);
}

// output projection: [4096][2048] fp32 = ao @ Wo^T
__global__ __launch_bounds__(256) void gemm_proj(
    const u16* __restrict__ ao, const u16* __restrict__ wob, float* __restrict__ out)
{
  const int r = blockIdx.x;   // 512
  gemm_core<true>(ao, wob, out, (r >> 4) * 128, (r & 15) * 128, 2048, 5555.f);
}

// ================= legacy GEMM (fp32-staging) — fallback path only =================
template <bool AF, bool WF, bool OF>
__global__ __launch_bounds__(256) void gemm_bt(
    const void* __restrict__ Ap,
    const void* __restrict__ Wp0, const void* __restrict__ Wp1, const void* __restrict__ Wp2,
    void* __restrict__ O0, void* __restrict__ O1, void* __restrict__ O2,
    int M, int N, int K, float sentinel)
{
  __shared__ __align__(16) u16 As[128 * 32];
  __shared__ __align__(16) u16 Bs[128 * 32];

  const void* Wp; void* O;
  if (blockIdx.z == 0)      { Wp = Wp0; O = O0; }
  else if (blockIdx.z == 1) { Wp = Wp1; O = O1; }
  else                      { Wp = Wp2; O = O2; }

  const float* Af = (const float*)Ap;  const u16* Ab = (const u16*)Ap;
  const float* Wf = (const float*)Wp;  const u16* Wb = (const u16*)Wp;

  const int tid  = threadIdx.x;
  const int wave = tid >> 6;
  const int lane = tid & 63;
  const int quad = lane >> 4;
  const int l15  = lane & 15;

  const int m0 = blockIdx.y * 128;
  const int n0 = blockIdx.x * 128;
  const int wm = (wave >> 1) * 64;
  const int wn = (wave & 1) * 64;

  const int e0 = wave * 1024 + lane * 8;
  const int e1 = e0 + 512;
  const int r0 = e0 >> 5, c0 = e0 & 31;
  const int r1 = e1 >> 5, c1 = e1 & 31;

  const long aoff0 = (long)(m0 + r0) * K + c0;
  const long aoff1 = (long)(m0 + r1) * K + c1;
  const long boff0 = (long)(n0 + r0) * K + c0;
  const long boff1 = (long)(n0 + r1) * K + c1;

  const f32x4 zero = {0.f, 0.f, 0.f, 0.f};
  f32x4 acc[4][4];
#pragma unroll
  for (int i = 0; i < 4; ++i)
#pragma unroll
    for (int j = 0; j < 4; ++j) acc[i][j] = zero;

  for (int k0 = 0; k0 < K; k0 += 32) {
    short8 a0, a1, b0, b1;
    if constexpr (AF) {
      a0 = ld8f(Af + aoff0 + k0);
      a1 = ld8f(Af + aoff1 + k0);
    } else {
      a0 = *(const short8*)(Ab + aoff0 + k0);
      a1 = *(const short8*)(Ab + aoff1 + k0);
    }
    if constexpr (WF) {
      b0 = ld8f(Wf + boff0 + k0);
      b1 = ld8f(Wf + boff1 + k0);
    } else {
      b0 = *(const short8*)(Wb + boff0 + k0);
      b1 = *(const short8*)(Wb + boff1 + k0);
    }

    __syncthreads();
    *(short8*)&As[e0] = a0;
    *(short8*)&As[e1] = a1;
    *(short8*)&Bs[e0] = b0;
    *(short8*)&Bs[e1] = b1;
    __syncthreads();

    short8 af[4], bf[4];
#pragma unroll
    for (int i = 0; i < 4; ++i)
      af[i] = *(const short8*)&As[(wm + i * 16 + l15) * 32 + quad * 8];
#pragma unroll
    for (int j = 0; j < 4; ++j)
      bf[j] = *(const short8*)&Bs[(wn + j * 16 + l15) * 32 + quad * 8];
#pragma unroll
    for (int i = 0; i < 4; ++i)
#pragma unroll
      for (int j = 0; j < 4; ++j)
        acc[i][j] = __builtin_amdgcn_mfma_f32_16x16x32_bf16(af[i], bf[j], acc[i][j], 0, 0, 0);
  }

#pragma unroll
  for (int i = 0; i < 4; ++i) {
    const int row0 = m0 + wm + i * 16 + quad * 4;
#pragma unroll
    for (int j = 0; j < 4; ++j) {
      const int col = n0 + wn + j * 16 + l15;
#pragma unroll
      for (int r = 0; r < 4; ++r) {
        const float val = flushv(acc[i][j][r], sentinel);
        if constexpr (OF)
          ((float*)O)[(long)(row0 + r) * N + col] = val;
        else
          ((u16*)O)[(long)(row0 + r) * N + col] = f2bf(val);
      }
    }
  }
}

// ================= RoPE (fallback path only; fast path fuses into gemm_qk8) =================
__global__ __launch_bounds__(256) void rope_kernel(u16* __restrict__ Q, u16* __restrict__ K)
{
  int t = blockIdx.x * 256 + threadIdx.x;
  const int per = 524288;              // 65536 rows * 8 i-groups
  u16* P = Q;
  if (t >= per) { P = K; t -= per; }
  const int i8  = t & 7;
  const int row = t >> 3;              // (b*2048 + s)*16 + h
  const int s   = (row >> 4) & 2047;
  const long off = (long)row * 128 + i8 * 8;

  short8 va = *(const short8*)&P[off];
  short8 vb = *(const short8*)&P[off + 64];

  const float fs = (float)s;
  float invf = __expf((float)(i8 * 8) * -0.14391156831212787f);  // 10000^(-i/64)
  const float step = 0.86596432336f;                             // 10000^(-1/64)
#pragma unroll
  for (int j = 0; j < 8; ++j) {
    float sn, cs;
    __sincosf(fs * invf, &sn, &cs);
    const float q1 = bf2f((u16)va[j]);
    const float q2 = bf2f((u16)vb[j]);
    va[j] = (short)f2bf(q1 * cs - q2 * sn);
    vb[j] = (short)f2bf(q1 * sn + q2 * cs);
    invf *= step;
  }
  *(short8*)&P[off]      = va;
  *(short8*)&P[off + 64] = vb;
}

// ================= causal flash attention (LDS-staged, lockstep, 2-phase) =================
__global__ __launch_bounds__(256, 4) void attn_kernel(
    const u16* __restrict__ Q, const u16* __restrict__ K,
    const u16* __restrict__ VT, u16* __restrict__ AO)
{
  __shared__ __align__(16) u16 Kb[2][4096];  // [32 key][128 d], unit^=(row&7) swizzle
  __shared__ __align__(16) u16 Vb[2][4096];  // [128 d][32 tok], unit^=((row>>1)&3)

  const int tid  = threadIdx.x;
  const int wave = tid >> 6;
  const int lane = tid & 63;
  const int quad = lane >> 4;
  const int l15  = lane & 15;

  const int lin = blockIdx.x;                 // 0..1023
  const int xcd = lin & 7;
  const int hi  = lin >> 8;                   // 0..3
  const int g   = (lin >> 3) & 31;            // 0..31
  const int qb  = (hi & 1) ? (31 - g) : g;
  const int bh  = (xcd << 2) | hi;
  const int b   = bh >> 4;
  const int h   = bh & 15;

  const long base = (long)b * 2048 * 2048 + (long)h * 128;
  const long vtb  = (long)h * 128 * 4096 + (long)b * 2048;
  const int q0w = qb * 64 + wave * 16;
  const int qi  = q0w + l15;

  const u16* Kp0 = K + base;
  const u16* Vp0 = VT + vtb;

  auto STAGE = [&](int bs, int jb) {
#pragma unroll
    for (int gi = 0; gi < 2; ++gi) {
      const int slot = wave * 2 + gi;
      {
        const int row = slot * 4 + (lane >> 4);
        const int su  = lane & 15;
        gl16(Kp0 + (long)(jb * 32 + row) * 2048 + ((su ^ (row & 7)) << 3),
             &Kb[bs][slot * 512]);
      }
      {
        const int row = slot * 16 + (lane >> 2);
        const int su  = lane & 3;
        gl16(Vp0 + (long)row * 4096 + jb * 32 + ((su ^ ((row >> 1) & 3)) << 3),
             &Vb[bs][slot * 512]);
      }
    }
  };

  short8 qa[4];
#pragma unroll
  for (int c = 0; c < 4; ++c)
    qa[c] = *(const short8*)&Q[base + (long)(q0w + l15) * 2048 + c * 32 + quad * 8];

  const f32x4 zero = {0.f, 0.f, 0.f, 0.f};
  f32x4 o[8];
#pragma unroll
  for (int c = 0; c < 8; ++c) o[c] = zero;

  float mreg = -1e30f, lreg = 0.f;
  const float scale = 0.08838834764831845f;  // 1/sqrt(128)

  const int njb_blk = qb * 2 + 2;
  const int njb_w   = qb * 2 + 1 + (wave >> 1);

  STAGE(0, 0);
  __syncthreads();

  const int xorK = l15 & 7;
  const int xorV = (l15 >> 1) & 3;

  int cur = 0;
  for (int jb = 0; jb < njb_blk; ++jb) {
    if (jb + 1 < njb_blk) STAGE(cur ^ 1, jb + 1);

    if (jb < njb_w) {
      const int j0 = jb * 32;

      f32x4 s0T = zero, s1T = zero;
#pragma unroll
      for (int c = 0; c < 4; ++c) {
        const short8 kA = *(const short8*)&Kb[cur][l15 * 128 + (((c * 4 + quad) ^ xorK) << 3)];
        const short8 kB2 = *(const short8*)&Kb[cur][(l15 + 16) * 128 + (((c * 4 + quad) ^ xorK) << 3)];
        s0T = __builtin_amdgcn_mfma_f32_16x16x32_bf16(kA, qa[c], s0T, 0, 0, 0);
        s1T = __builtin_amdgcn_mfma_f32_16x16x32_bf16(kB2, qa[c], s1T, 0, 0, 0);
      }

      float sv0[4], sv1[4];
      float pmax = -1e30f;
      if (j0 + 31 > q0w) {
#pragma unroll
        for (int r = 0; r < 4; ++r) {
          const int k0i = j0 + quad * 4 + r;
          float s0 = s0T[r] * scale; if (k0i > qi)      s0 = -1e30f;
          float s1 = s1T[r] * scale; if (k0i + 16 > qi) s1 = -1e30f;
          sv0[r] = s0; sv1[r] = s1;
          pmax = fmaxf(pmax, fmaxf(s0, s1));
        }
      } else {
#pragma unroll
        for (int r = 0; r < 4; ++r) {
          sv0[r] = s0T[r] * scale;
          sv1[r] = s1T[r] * scale;
          pmax = fmaxf(pmax, fmaxf(sv0[r], sv1[r]));
        }
      }
      pmax = fmaxf(pmax, __shfl_xor(pmax, 16, 64));
      pmax = fmaxf(pmax, __shfl_xor(pmax, 32, 64));
      const float mprev = mreg;
      const float mnew  = fmaxf(mprev, pmax);
      const float alpha = __expf(mprev - mnew);
      float psum = 0.f;
#pragma unroll
      for (int r = 0; r < 4; ++r) {
        sv0[r] = __expf(sv0[r] - mnew);
        sv1[r] = __expf(sv1[r] - mnew);
        psum += sv0[r] + sv1[r];
      }
      psum += __shfl_xor(psum, 16, 64);
      psum += __shfl_xor(psum, 32, 64);
      lreg = lreg * alpha + psum;
      mreg = mnew;

      int w0, w1, w2, w3;
      asm("v_cvt_pk_bf16_f32 %0, %1, %2" : "=v"(w0) : "v"(sv0[0]), "v"(sv0[1]));
      asm("v_cvt_pk_bf16_f32 %0, %1, %2" : "=v"(w1) : "v"(sv0[2]), "v"(sv0[3]));
      asm("v_cvt_pk_bf16_f32 %0, %1, %2" : "=v"(w2) : "v"(sv1[0]), "v"(sv1[1]));
      asm("v_cvt_pk_bf16_f32 %0, %1, %2" : "=v"(w3) : "v"(sv1[2]), "v"(sv1[3]));
      const int srcA = l15 + ((quad & 1) << 5);
      const int srcB = srcA + 16;
      const int a0 = __shfl(w0, srcA, 64), a1 = __shfl(w1, srcA, 64);
      const int a2 = __shfl(w0, srcB, 64), a3 = __shfl(w1, srcB, 64);
      const int h0 = __shfl(w2, srcA, 64), h1 = __shfl(w3, srcA, 64);
      const int h2 = __shfl(w2, srcB, 64), h3 = __shfl(w3, srcB, 64);
      const bool hiq = quad >= 2;
      i32x4 pt;
      pt[0] = hiq ? h0 : a0;
      pt[1] = hiq ? h1 : a1;
      pt[2] = hiq ? h2 : a2;
      pt[3] = hiq ? h3 : a3;
      const short8 pa = *(const short8*)&pt;

      float av[4];
#pragma unroll
      for (int r = 0; r < 4; ++r) av[r] = __shfl(alpha, quad * 4 + r, 64);
#pragma unroll
      for (int c = 0; c < 8; ++c) {
        o[c][0] *= av[0]; o[c][1] *= av[1]; o[c][2] *= av[2]; o[c][3] *= av[3];
      }

#pragma unroll
      for (int c = 0; c < 8; ++c) {
        const short8 vf = *(const short8*)&Vb[cur][(c * 16 + l15) * 32 + ((quad ^ xorV) << 3)];
        o[c] = __builtin_amdgcn_mfma_f32_16x16x32_bf16(pa, vf, o[c], 0, 0, 0);
      }
    }

    __syncthreads();
    cur ^= 1;
  }

#pragma unroll
  for (int r = 0; r < 4; ++r) {
    const float lr  = __shfl(lreg, quad * 4 + r, 64);
    const float inv = 1.0f / lr;
    const long rowoff = base + (long)(q0w + quad * 4 + r) * 2048;
#pragma unroll
    for (int c = 0; c < 8; ++c)
      AO[rowoff + c * 16 + l15] = f2bf(flushv(o[c][r] * inv, 9999.f));
  }
}

// ================= diagnostic fill =================
__global__ __launch_bounds__(256) void fill_kernel(float* __restrict__ out, long n, float v)
{
  const long t = (long)blockIdx.x * 256 + threadIdx.x;
  if (t < n) out[t] = v;
}

// ================= launch =================
extern "C" void kernel_launch(void* const* d_in, const int* in_sizes, int n_in,
                              void* d_out, int out_size, void* d_ws, size_t ws_size,
                              hipStream_t stream)
{
  // Inputs fp32 (x, Wq, Wk, Wv, Wo); OUTPUT fp32 (reference dtype).
  const float* x  = (const float*)d_in[0];
  const float* Wq = (const float*)d_in[1];
  const float* Wk = (const float*)d_in[2];
  const float* Wv = (const float*)d_in[3];
  const float* Wo = (const float*)d_in[4];
  float* out = (float*)d_out;

  const long QSZ = (long)2 * 2048 * 2048;  // 8388608 elems
  const long WSZ = QSZ / 2;                // 2048*2048 weight elems

  u16* ws = (u16*)d_ws;
  u16* q  = ws;            // bf16 internal
  u16* k  = ws + QSZ;
  u16* v  = ws + 2 * QSZ;  // V^T: [2048 d][4096 tok]
  u16* ao = q;             // attention output in-place over q (partition-safe)

  if (ws_size >= (size_t)6 * QSZ * sizeof(u16)) {
    // ---- fast path: bf16 pre-convert + depth-2 QK GEMM (fused RoPE) + 128^2 VT/proj ----
    u16* xb  = ws + 3 * QSZ;        // x as bf16 [4096][2048]
    u16* wqb = ws + 4 * QSZ;
    u16* wkb = wqb + WSZ;
    u16* wvb = wqb + 2 * WSZ;
    u16* wob = wqb + 3 * WSZ;

    cvt_all<<<12288, 256, 0, stream>>>(x, Wq, Wk, Wv, Wo, xb, wqb, wkb, wvb, wob);
    gemm_qk8<<<256, 512, 0, stream>>>(xb, wqb, wkb, q, k);   // rope fused in epilogue
    gemm_vt<<<512, 256, 0, stream>>>(wvb, xb, v);
    attn_kernel<<<1024, 256, 0, stream>>>(q, k, v, ao);
    gemm_proj<<<512, 256, 0, stream>>>(ao, wob, out);
    return;
  }

  // ---- fallback: R5 path (fp32-staging GEMMs + separate rope), needs 48 MB ----
  if (ws_size < (size_t)3 * QSZ * sizeof(u16)) {
    fill_kernel<<<(int)((QSZ + 255) / 256), 256, 0, stream>>>(out, QSZ, 1111.f);
    return;
  }

  gemm_bt<true, true, false><<<dim3(16, 32, 2), 256, 0, stream>>>(
      x, Wq, Wk, Wk, q, k, k, 4096, 2048, 2048, 7777.f);
  gemm_bt<true, true, false><<<dim3(32, 16, 1), 256, 0, stream>>>(
      Wv, x, x, x, v, v, v, 2048, 4096, 2048, 7777.f);
  rope_kernel<<<4096, 256, 0, stream>>>(q, k);
  attn_kernel<<<1024, 256, 0, stream>>>(q, k, v, ao);
  gemm_bt<false, true, true><<<dim3(16, 32, 1), 256, 0, stream>>>(
      ao, Wo, Wo, Wo, out, out, out, 4096, 2048, 2048, 5555.f);
}